// Round 3
// baseline (228.606 us; speedup 1.0000x reference)
//
#include <hip/hip_runtime.h>
#include <hip/hip_bf16.h>

#define SLEN 2048
#define DMODEL 1024
#define NHEAD 8
#define DHEAD 128
#define BM 128
#define BKT 64
#define KPITCH 136  // K-tile row: 128 fp16 cols + 8 pad
#define CPITCH 72   // C/Vt-tile row: 64 fp16 cols + 8 pad
#define QSCALE 0.08838834764831845f  // 1/sqrt(128)

typedef __attribute__((ext_vector_type(4))) float f32x4;
typedef __attribute__((ext_vector_type(8))) _Float16 f16x8;
typedef __attribute__((ext_vector_type(4))) _Float16 f16x4;

// ---------------- Kernel 1: gate preactivations (simple, atomic-free) -------
__global__ __launch_bounds__(256)
void gates_kernel(const float* __restrict__ q, const float* __restrict__ k,
                  const float* __restrict__ v, const float* __restrict__ igw,
                  const float* __restrict__ fgw, float* __restrict__ gpre) {
  const int row = blockIdx.x;
  const int tid = threadIdx.x;
  float acc[16];
  #pragma unroll
  for (int g = 0; g < 16; ++g) acc[g] = 0.f;
  for (int c = tid; c < 3072; c += 256) {
    float x;
    if (c < 1024)      x = q[(size_t)row * 1024 + c];
    else if (c < 2048) x = k[(size_t)row * 1024 + c - 1024];
    else               x = v[(size_t)row * 1024 + c - 2048];
    #pragma unroll
    for (int g = 0; g < 8; ++g) acc[g] += x * igw[(size_t)g * 3072 + c];
    #pragma unroll
    for (int g = 0; g < 8; ++g) acc[8 + g] += x * fgw[(size_t)g * 3072 + c];
  }
  __shared__ float red[16][4];
  const int lane = tid & 63, wid = tid >> 6;
  #pragma unroll
  for (int g = 0; g < 16; ++g) {
    float r = acc[g];
    #pragma unroll
    for (int m = 1; m < 64; m <<= 1) r += __shfl_xor(r, m);
    if (lane == 0) red[g][wid] = r;
  }
  __syncthreads();
  if (tid < 16)
    gpre[(size_t)tid * 4096 + row] = red[tid][0] + red[tid][1] + red[tid][2] + red[tid][3];
}

// ---------------- Kernel 2: per-(b,h) scans (serial, obviously correct) -----
__global__ __launch_bounds__(256)
void scan_kernel(const float* __restrict__ gpre, const float* __restrict__ igb,
                 const float* __restrict__ fgb, float* __restrict__ a_out,
                 float* __restrict__ ms_out, float* __restrict__ fl_out) {
  const int bh = blockIdx.x;            // b*8 + h
  const int h = bh & 7;
  const int b = bh >> 3;
  const int tid = threadIdx.x;
  __shared__ double sbd[256];
  __shared__ float sbf[256];
  const int base = b * 2048 + tid * 8;
  const float ig_b = igb[h], fg_b = fgb[h];
  double cs[8];
  float av[8];
  double tot = 0.0;
  #pragma unroll
  for (int e = 0; e < 8; ++e) {
    float x = gpre[(size_t)(8 + h) * 4096 + base + e] + fg_b;
    float l = fminf(x, 0.f) - log1pf(__expf(-fabsf(x)));   // log_sigmoid
    tot += (double)l;
    cs[e] = tot;
  }
  sbd[tid] = tot;
  __syncthreads();
  if (tid == 0) {
    double run = 0.0;
    for (int i = 0; i < 256; ++i) { double t2 = sbd[i]; sbd[i] = run; run += t2; }
  }
  __syncthreads();
  const double excl = sbd[tid];
  float mtot = -3.4e38f;
  #pragma unroll
  for (int e = 0; e < 8; ++e) {
    cs[e] += excl;
    float ig = gpre[(size_t)h * 4096 + base + e] + ig_b;
    av[e] = (float)((double)ig - cs[e]);
    mtot = fmaxf(mtot, av[e]);
  }
  sbf[tid] = mtot;
  __syncthreads();
  if (tid == 0) {
    float run = -3.4e38f;
    for (int i = 0; i < 256; ++i) { float t2 = sbf[i]; sbf[i] = run; run = fmaxf(run, t2); }
  }
  __syncthreads();
  float run = sbf[tid];
  const int obase = bh * 2048 + tid * 8;
  #pragma unroll
  for (int e = 0; e < 8; ++e) {
    run = fmaxf(run, av[e]);
    a_out[obase + e] = av[e];
    ms_out[obase + e] = run;
    fl_out[obase + e] = __expf(-(float)(cs[e] + (double)run));  // exp(-max_log_D)
  }
}

// ---------------- Kernel 3: main causal mLSTM (fp16 split-precision MFMA) ---
// grid 256 = (qtile 0..15) x (bh 0..15); 8 waves = 4 row-groups x 2 col-groups.
// Q (scaled) lives in registers as hi/lo fp16 frags; K/V/C staged hi/lo in LDS.
__global__ __launch_bounds__(512, 1)
void mlstm_main(const float* __restrict__ q, const float* __restrict__ k,
                const float* __restrict__ v, const float* __restrict__ a_g,
                const float* __restrict__ ms_g, const float* __restrict__ fl_g,
                float* __restrict__ out) {
  __shared__ __align__(16) _Float16 Ks_hi[BKT * KPITCH];
  __shared__ __align__(16) _Float16 Ks_lo[BKT * KPITCH];
  __shared__ __align__(16) _Float16 Vts_hi[DHEAD * CPITCH];  // [dv][j]
  __shared__ __align__(16) _Float16 Vts_lo[DHEAD * CPITCH];
  __shared__ __align__(16) _Float16 Cs_hi[BM * CPITCH];
  __shared__ __align__(16) _Float16 Cs_lo[BM * CPITCH];
  __shared__ float a_s[BKT];
  __shared__ float rs_lds[BM][2];

  const int bid = blockIdx.x;
  const int t = bid >> 4;
  const int bh = bid & 15;
  const int b = bh >> 3, h = bh & 7;
  const int i0 = t * BM;
  const int tid = threadIdx.x;
  const int lane = tid & 63;
  const int wid = tid >> 6;
  const int wr = wid >> 1;      // row group 0..3 (32 rows each)
  const int wc = wid & 1;       // col group 0..1
  const int l15 = lane & 15;
  const int lg = lane >> 4;

  const f32x4 z4 = {0.f, 0.f, 0.f, 0.f};

  // ---- Q fragments to registers (QSCALE folded, hi/lo split) ----
  f16x8 qh[2][4], ql[2][4];
  #pragma unroll
  for (int rf = 0; rf < 2; ++rf) {
    const int row = wr * 32 + rf * 16 + l15;
    const float* qbase = q + (size_t)(b * SLEN + i0 + row) * DMODEL + h * DHEAD;
    #pragma unroll
    for (int ks = 0; ks < 4; ++ks) {
      f32x4 x0 = *(const f32x4*)(qbase + ks * 32 + lg * 8);
      f32x4 x1 = *(const f32x4*)(qbase + ks * 32 + lg * 8 + 4);
      f16x8 hi, lo;
      #pragma unroll
      for (int e = 0; e < 4; ++e) {
        float s0 = x0[e] * QSCALE, s1 = x1[e] * QSCALE;
        _Float16 h0 = (_Float16)s0, h1 = (_Float16)s1;
        hi[e] = h0;     hi[e + 4] = h1;
        lo[e] = (_Float16)(s0 - (float)h0);
        lo[e + 4] = (_Float16)(s1 - (float)h1);
      }
      qh[rf][ks] = hi; ql[rf][ks] = lo;
    }
  }

  float ms_reg[8], fl_reg[8];
  {
    const float* mp = ms_g + bh * SLEN + i0 + wr * 32;
    const float* fp = fl_g + bh * SLEN + i0 + wr * 32;
    #pragma unroll
    for (int rf = 0; rf < 2; ++rf)
      #pragma unroll
      for (int rr2 = 0; rr2 < 4; ++rr2) {
        const int il = rf * 16 + lg * 4 + rr2;
        ms_reg[rf * 4 + rr2] = mp[il];
        fl_reg[rf * 4 + rr2] = fp[il];
      }
  }

  f32x4 hacc[2][4];
  #pragma unroll
  for (int a1 = 0; a1 < 2; ++a1)
    #pragma unroll
    for (int a2 = 0; a2 < 4; ++a2) hacc[a1][a2] = z4;
  float ps[2][4] = {{0.f, 0.f, 0.f, 0.f}, {0.f, 0.f, 0.f, 0.f}};

  const int jt_max = 2 * t + 1;
  for (int jt = 0; jt <= jt_max; ++jt) {
    const int j0 = jt * BKT;
    const int joff = j0 - i0;     // mask col jj iff jj + joff > il
    __syncthreads();              // staging vs previous iteration's reads
    // stage K tile hi/lo: 64 rows x 128 cols
    {
      const int rr = tid >> 5;            // 0..15
      const int cc = (tid & 31) * 4;      // 0..124
      const size_t rowK = (size_t)(b * SLEN + j0) * DMODEL + h * DHEAD;
      #pragma unroll
      for (int p = 0; p < 4; ++p) {
        const int row = p * 16 + rr;
        f32x4 xv = *(const f32x4*)(k + rowK + (size_t)row * DMODEL + cc);
        f16x4 hi, lo;
        #pragma unroll
        for (int e = 0; e < 4; ++e) {
          _Float16 hh = (_Float16)xv[e];
          hi[e] = hh; lo[e] = (_Float16)(xv[e] - (float)hh);
        }
        *(f16x4*)&Ks_hi[row * KPITCH + cc] = hi;
        *(f16x4*)&Ks_lo[row * KPITCH + cc] = lo;
      }
    }
    // stage V tile transposed hi/lo: [dv 0..127][j 0..63]
    {
      const int j = tid >> 3;             // 0..63
      const int dvb = (tid & 7) * 16;     // 0..112
      const float* vp = v + (size_t)(b * SLEN + j0 + j) * DMODEL + h * DHEAD;
      #pragma unroll
      for (int p = 0; p < 4; ++p) {
        const int dv = dvb + p * 4;
        f32x4 xv = *(const f32x4*)(vp + dv);
        #pragma unroll
        for (int e = 0; e < 4; ++e) {
          _Float16 hh = (_Float16)xv[e];
          Vts_hi[(dv + e) * CPITCH + j] = hh;
          Vts_lo[(dv + e) * CPITCH + j] = (_Float16)(xv[e] - (float)hh);
        }
      }
    }
    if (tid < BKT) a_s[tid] = a_g[bh * SLEN + j0 + tid];
    __syncthreads();

    // QK^T (split: qh*kh + ql*kh + qh*kl): rows wr*32+{0..31}, cols wc*32+{0..31}
    f32x4 sacc[2][2];
    #pragma unroll
    for (int a1 = 0; a1 < 2; ++a1)
      #pragma unroll
      for (int a2 = 0; a2 < 2; ++a2) sacc[a1][a2] = z4;
    #pragma unroll
    for (int ks = 0; ks < 4; ++ks) {
      #pragma unroll
      for (int cf = 0; cf < 2; ++cf) {
        const int krow = wc * 32 + cf * 16 + l15;
        f16x8 bhf = *(const f16x8*)&Ks_hi[krow * KPITCH + ks * 32 + lg * 8];
        f16x8 blf = *(const f16x8*)&Ks_lo[krow * KPITCH + ks * 32 + lg * 8];
        #pragma unroll
        for (int rf = 0; rf < 2; ++rf) {
          sacc[rf][cf] = __builtin_amdgcn_mfma_f32_16x16x32_f16(qh[rf][ks], bhf, sacc[rf][cf], 0, 0, 0);
          sacc[rf][cf] = __builtin_amdgcn_mfma_f32_16x16x32_f16(ql[rf][ks], bhf, sacc[rf][cf], 0, 0, 0);
          sacc[rf][cf] = __builtin_amdgcn_mfma_f32_16x16x32_f16(qh[rf][ks], blf, sacc[rf][cf], 0, 0, 0);
        }
      }
    }
    // elementwise: decay, causal mask, rowsum partials, C -> LDS hi/lo
    #pragma unroll
    for (int rf = 0; rf < 2; ++rf) {
      #pragma unroll
      for (int cf = 0; cf < 2; ++cf) {
        const int jj = wc * 32 + cf * 16 + l15;
        const float aj = a_s[jj];
        #pragma unroll
        for (int rr2 = 0; rr2 < 4; ++rr2) {
          const int il = wr * 32 + rf * 16 + lg * 4 + rr2;
          const float e = __expf(fminf(aj - ms_reg[rf * 4 + rr2], 0.f));
          float val = sacc[rf][cf][rr2] * e;
          if (jj + joff > il) val = 0.f;   // causal mask (only bites on diag tiles)
          ps[rf][rr2] += val;
          _Float16 chh = (_Float16)val;
          Cs_hi[il * CPITCH + jj] = chh;
          Cs_lo[il * CPITCH + jj] = (_Float16)(val - (float)chh);
        }
      }
    }
    __syncthreads();   // full C tile visible before PV
    // PV (split: ch*vh + cl*vh + ch*vl): rows wr*32+{0..31}, dv wc*64+{0..63}
    #pragma unroll
    for (int ks = 0; ks < 2; ++ks) {
      f16x8 cah[2], cal[2];
      #pragma unroll
      for (int rf = 0; rf < 2; ++rf) {
        const int crow = wr * 32 + rf * 16 + l15;
        cah[rf] = *(const f16x8*)&Cs_hi[crow * CPITCH + ks * 32 + lg * 8];
        cal[rf] = *(const f16x8*)&Cs_lo[crow * CPITCH + ks * 32 + lg * 8];
      }
      #pragma unroll
      for (int cf = 0; cf < 4; ++cf) {
        const int vrow = wc * 64 + cf * 16 + l15;
        f16x8 vbh = *(const f16x8*)&Vts_hi[vrow * CPITCH + ks * 32 + lg * 8];
        f16x8 vbl = *(const f16x8*)&Vts_lo[vrow * CPITCH + ks * 32 + lg * 8];
        #pragma unroll
        for (int rf = 0; rf < 2; ++rf) {
          hacc[rf][cf] = __builtin_amdgcn_mfma_f32_16x16x32_f16(cah[rf], vbh, hacc[rf][cf], 0, 0, 0);
          hacc[rf][cf] = __builtin_amdgcn_mfma_f32_16x16x32_f16(cal[rf], vbh, hacc[rf][cf], 0, 0, 0);
          hacc[rf][cf] = __builtin_amdgcn_mfma_f32_16x16x32_f16(cah[rf], vbl, hacc[rf][cf], 0, 0, 0);
        }
      }
    }
  }

  // rowsum: reduce across 16-lane groups, then across the 2 col-wave-groups
  #pragma unroll
  for (int rf = 0; rf < 2; ++rf)
    #pragma unroll
    for (int rr2 = 0; rr2 < 4; ++rr2) {
      float vsum = ps[rf][rr2];
      #pragma unroll
      for (int m = 1; m < 16; m <<= 1) vsum += __shfl_xor(vsum, m);
      if (l15 == 0) rs_lds[wr * 32 + rf * 16 + lg * 4 + rr2][wc] = vsum;
    }
  __syncthreads();
  // finalize: norm = max(|rowsum|, exp(-max_log_D)) + eps; write h
  #pragma unroll
  for (int rf = 0; rf < 2; ++rf) {
    #pragma unroll
    for (int rr2 = 0; rr2 < 4; ++rr2) {
      const int il = wr * 32 + rf * 16 + lg * 4 + rr2;
      const float rsum = rs_lds[il][0] + rs_lds[il][1];
      const float inv = 1.0f / (fmaxf(fabsf(rsum), fl_reg[rf * 4 + rr2]) + 1e-6f);
      const size_t orow = (size_t)(b * SLEN + i0 + il) * DMODEL + h * DHEAD;
      #pragma unroll
      for (int cf = 0; cf < 4; ++cf)
        out[orow + wc * 64 + cf * 16 + l15] = hacc[rf][cf][rr2] * inv;
    }
  }
}

// ---------------- Kernel 4: in-place LayerNorm on d_out ---------------------
__global__ __launch_bounds__(256)
void ln_kernel(float* __restrict__ out, const float* __restrict__ gamma) {
  const int row = blockIdx.x;
  const int tid = threadIdx.x;
  float* x = out + (size_t)row * DMODEL;
  f32x4 xv = ((const f32x4*)x)[tid];
  float s = xv[0] + xv[1] + xv[2] + xv[3];
  float qq = xv[0] * xv[0] + xv[1] * xv[1] + xv[2] * xv[2] + xv[3] * xv[3];
  #pragma unroll
  for (int m = 1; m < 64; m <<= 1) { s += __shfl_xor(s, m); qq += __shfl_xor(qq, m); }
  __shared__ float ss[4], sq[4];
  const int wid = tid >> 6;
  if ((tid & 63) == 0) { ss[wid] = s; sq[wid] = qq; }
  __syncthreads();
  s = ss[0] + ss[1] + ss[2] + ss[3];
  qq = sq[0] + sq[1] + sq[2] + sq[3];
  const float mu = s * (1.f / 1024.f);
  const float var = qq * (1.f / 1024.f) - mu * mu;
  const float rstd = rsqrtf(var + 1e-5f);
  f32x4 g = ((const f32x4*)gamma)[tid];
  f32x4 ov;
  ov[0] = (xv[0] - mu) * rstd * g[0];
  ov[1] = (xv[1] - mu) * rstd * g[1];
  ov[2] = (xv[2] - mu) * rstd * g[2];
  ov[3] = (xv[3] - mu) * rstd * g[3];
  ((f32x4*)x)[tid] = ov;
}

extern "C" void kernel_launch(void* const* d_in, const int* in_sizes, int n_in,
                              void* d_out, int out_size, void* d_ws, size_t ws_size,
                              hipStream_t stream) {
  (void)in_sizes; (void)n_in; (void)out_size; (void)ws_size;
  const float* q   = (const float*)d_in[0];
  const float* k   = (const float*)d_in[1];
  const float* v   = (const float*)d_in[2];
  const float* igw = (const float*)d_in[3];
  const float* igb = (const float*)d_in[4];
  const float* fgw = (const float*)d_in[5];
  const float* fgb = (const float*)d_in[6];
  const float* lns = (const float*)d_in[7];
  float* out = (float*)d_out;

  float* gpre = (float*)d_ws;            // [16][4096]
  float* a_g  = gpre + 16 * 4096;        // [16][2048]
  float* ms_g = a_g + 16 * 2048;         // [16][2048]
  float* fl_g = ms_g + 16 * 2048;        // [16][2048]

  gates_kernel<<<dim3(4096), dim3(256), 0, stream>>>(q, k, v, igw, fgw, gpre);
  scan_kernel<<<dim3(16), dim3(256), 0, stream>>>(gpre, igb, fgb, a_g, ms_g, fl_g);
  mlstm_main<<<dim3(256), dim3(512), 0, stream>>>(q, k, v, a_g, ms_g, fl_g, out);
  ln_kernel<<<dim3(4096), dim3(256), 0, stream>>>(out, lns);
}

// Round 5
// 224.665 us; speedup vs baseline: 1.0175x; 1.0175x over previous
//
#include <hip/hip_runtime.h>
#include <hip/hip_bf16.h>

#define SLEN 2048
#define DMODEL 1024
#define NHEAD 8
#define DHEAD 128
#define BM 64
#define BKT 64
#define QSCALE 0.08838834764831845f  // 1/sqrt(128)

typedef __attribute__((ext_vector_type(4))) float f32x4;
typedef __attribute__((ext_vector_type(8))) _Float16 f16x8;
typedef __attribute__((ext_vector_type(4))) _Float16 f16x4;

// ---------------- Kernel 1: gate preactivations -----------------------------
// gpre[g][row], g 0..7 = ig head g, 8..15 = fg head g-8; row = b*2048+s (4096)
// 256 blocks x 16 rows; X tile staged in LDS; W streamed (L2-resident, 50MB).
__global__ __launch_bounds__(256)
void gates_kernel(const float* __restrict__ q, const float* __restrict__ k,
                  const float* __restrict__ v, const float* __restrict__ igw,
                  const float* __restrict__ fgw, float* __restrict__ gpre) {
  __shared__ __align__(16) float X[16][516];
  const int row0 = blockIdx.x * 16;
  const int tid = threadIdx.x;
  const int r = tid >> 4;          // 0..15 output row
  const int g = tid & 15;          // 0..15 gate
  const float* wsrc = (g < 8) ? (igw + (size_t)g * 3072) : (fgw + (size_t)(g - 8) * 3072);
  float acc = 0.f;
  for (int kc = 0; kc < 3072; kc += 512) {
    const float* src; int col;
    if (kc < 1024)      { src = q; col = kc; }
    else if (kc < 2048) { src = k; col = kc - 1024; }
    else                { src = v; col = kc - 2048; }
    __syncthreads();
    {
      const int rr = tid >> 4;
      const int c0 = (tid & 15) * 4;
      const float* sp = src + (size_t)(row0 + rr) * DMODEL + col;
      #pragma unroll
      for (int p = 0; p < 8; ++p)
        *(f32x4*)&X[rr][c0 + p * 64] = *(const f32x4*)(sp + c0 + p * 64);
    }
    __syncthreads();
    #pragma unroll 4
    for (int kk = 0; kk < 512; kk += 4) {
      f32x4 xv = *(const f32x4*)&X[r][kk];
      f32x4 wv = *(const f32x4*)(wsrc + kc + kk);
      acc += xv[0] * wv[0] + xv[1] * wv[1] + xv[2] * wv[2] + xv[3] * wv[3];
    }
  }
  gpre[(size_t)g * 4096 + row0 + r] = acc;
}

// ---------------- Kernel 2: per-(b,h) scans (serial, obviously correct) -----
__global__ __launch_bounds__(256)
void scan_kernel(const float* __restrict__ gpre, const float* __restrict__ igb,
                 const float* __restrict__ fgb, float* __restrict__ a_out,
                 float* __restrict__ ms_out, float* __restrict__ fl_out) {
  const int bh = blockIdx.x;            // b*8 + h
  const int h = bh & 7;
  const int b = bh >> 3;
  const int tid = threadIdx.x;
  __shared__ double sbd[256];
  __shared__ float sbf[256];
  const int base = b * 2048 + tid * 8;
  const float ig_b = igb[h], fg_b = fgb[h];
  double cs[8];
  float av[8];
  double tot = 0.0;
  #pragma unroll
  for (int e = 0; e < 8; ++e) {
    float x = gpre[(size_t)(8 + h) * 4096 + base + e] + fg_b;
    float l = fminf(x, 0.f) - log1pf(__expf(-fabsf(x)));   // log_sigmoid
    tot += (double)l;
    cs[e] = tot;
  }
  sbd[tid] = tot;
  __syncthreads();
  if (tid == 0) {
    double run = 0.0;
    for (int i = 0; i < 256; ++i) { double t2 = sbd[i]; sbd[i] = run; run += t2; }
  }
  __syncthreads();
  const double excl = sbd[tid];
  float mtot = -3.4e38f;
  #pragma unroll
  for (int e = 0; e < 8; ++e) {
    cs[e] += excl;
    float ig = gpre[(size_t)h * 4096 + base + e] + ig_b;
    av[e] = (float)((double)ig - cs[e]);
    mtot = fmaxf(mtot, av[e]);
  }
  sbf[tid] = mtot;
  __syncthreads();
  if (tid == 0) {
    float run = -3.4e38f;
    for (int i = 0; i < 256; ++i) { float t2 = sbf[i]; sbf[i] = run; run = fmaxf(run, t2); }
  }
  __syncthreads();
  float run = sbf[tid];
  const int obase = bh * 2048 + tid * 8;
  #pragma unroll
  for (int e = 0; e < 8; ++e) {
    run = fmaxf(run, av[e]);
    a_out[obase + e] = av[e];
    ms_out[obase + e] = run;
    fl_out[obase + e] = __expf(-(float)(cs[e] + (double)run));  // exp(-max_log_D)
  }
}

// ---------------- Kernel 3: main causal mLSTM (fp16 split QK, plain PV) -----
// grid 512: heavy half (t=31..16) dispatched first, light half (t=0..15) after
// -> co-resident block pairs sum to ~33 iterations. 8 waves = 4 row x 2 col.
// LDS tiles XOR-swizzled (byte ^= (row&7)<<4) for 2-way-max bank access.
__global__ __launch_bounds__(512, 4)
void mlstm_main(const float* __restrict__ q, const float* __restrict__ k,
                const float* __restrict__ v, const float* __restrict__ a_g,
                const float* __restrict__ ms_g, const float* __restrict__ fl_g,
                float* __restrict__ out) {
  __shared__ __align__(16) _Float16 Ks_hi[BKT * 128];   // [64][128], 256B rows
  __shared__ __align__(16) _Float16 Ks_lo[BKT * 128];
  __shared__ __align__(16) _Float16 Vts[DHEAD * BKT];   // [dv 128][j 64], 128B rows
  __shared__ __align__(16) _Float16 Cs[BM * BKT];       // [i 64][j 64], 128B rows
  __shared__ float a_s[BKT];
  __shared__ float rs_lds[BM][2];

  const int bid = blockIdx.x;
  int t, bh;
  if (bid < 256) { t = 31 - (bid >> 4); bh = bid & 15; }      // heavy first
  else           { t = (bid - 256) >> 4; bh = (bid - 256) & 15; }
  const int b = bh >> 3, h = bh & 7;
  const int i0 = t * BM;
  const int tid = threadIdx.x;
  const int lane = tid & 63;
  const int wid = tid >> 6;
  const int wr = wid >> 1;      // row group 0..3 (16 rows each)
  const int wc = wid & 1;       // col group 0..1
  const int l15 = lane & 15;
  const int lg = lane >> 4;

  const f32x4 z4 = {0.f, 0.f, 0.f, 0.f};

  // ---- Q fragments to registers (QSCALE folded, hi/lo split) ----
  f16x8 qh[4], ql[4];
  {
    const float* qbase = q + (size_t)(b * SLEN + i0 + wr * 16 + l15) * DMODEL + h * DHEAD;
    #pragma unroll
    for (int ks = 0; ks < 4; ++ks) {
      f32x4 x0 = *(const f32x4*)(qbase + ks * 32 + lg * 8);
      f32x4 x1 = *(const f32x4*)(qbase + ks * 32 + lg * 8 + 4);
      f16x8 hi, lo;
      #pragma unroll
      for (int e = 0; e < 4; ++e) {
        float s0 = x0[e] * QSCALE, s1 = x1[e] * QSCALE;
        _Float16 h0 = (_Float16)s0, h1 = (_Float16)s1;
        hi[e] = h0;     hi[e + 4] = h1;
        lo[e] = (_Float16)(s0 - (float)h0);
        lo[e + 4] = (_Float16)(s1 - (float)h1);
      }
      qh[ks] = hi; ql[ks] = lo;
    }
  }

  float ms_reg[4], fl_reg[4];
  {
    const float* mp = ms_g + bh * SLEN + i0 + wr * 16;
    const float* fp = fl_g + bh * SLEN + i0 + wr * 16;
    #pragma unroll
    for (int rr2 = 0; rr2 < 4; ++rr2) {
      ms_reg[rr2] = mp[lg * 4 + rr2];
      fl_reg[rr2] = fp[lg * 4 + rr2];
    }
  }

  f32x4 hacc[4];
  #pragma unroll
  for (int a2 = 0; a2 < 4; ++a2) hacc[a2] = z4;
  float ps[4] = {0.f, 0.f, 0.f, 0.f};

  for (int jt = 0; jt <= t; ++jt) {
    const int j0 = jt * BKT;
    const int joff = j0 - i0;     // mask col jj iff jj + joff > il
    __syncthreads();              // staging vs previous iteration's reads
    // ---- stage K tile hi/lo: [64][128], swizzled ----
    {
      const int row = tid >> 3;             // 0..63
      const int c0 = (tid & 7) * 16;        // fp16 col chunk
      const float* kp = k + (size_t)(b * SLEN + j0 + row) * DMODEL + h * DHEAD + c0;
      char* bh_ = (char*)Ks_hi + row * 256;
      char* bl_ = (char*)Ks_lo + row * 256;
      const int sw = (row & 7) << 4;
      #pragma unroll
      for (int e = 0; e < 4; ++e) {
        f32x4 xv = *(const f32x4*)(kp + e * 4);
        f16x4 hi, lo;
        #pragma unroll
        for (int u = 0; u < 4; ++u) {
          _Float16 hh = (_Float16)xv[u];
          hi[u] = hh; lo[u] = (_Float16)(xv[u] - (float)hh);
        }
        const int bc = (c0 + e * 4) * 2;    // 8B-aligned byte col
        *(f16x4*)(bh_ + (bc ^ sw)) = hi;
        *(f16x4*)(bl_ + (bc ^ sw)) = lo;
      }
    }
    // ---- stage V transposed: Vts[dv][j], j = lane-varying (2-way max) ----
    {
      const int j = tid & 63;
      const int grp = tid >> 6;             // 0..7
      const float* vp = v + (size_t)(b * SLEN + j0 + j) * DMODEL + h * DHEAD;
      #pragma unroll
      for (int c = 0; c < 4; ++c) {
        const int dv0 = grp * 16 + c * 4;
        f32x4 xv = *(const f32x4*)(vp + dv0);
        #pragma unroll
        for (int e = 0; e < 4; ++e) {
          const int dv = dv0 + e;
          *(_Float16*)((char*)Vts + dv * 128 + ((j * 2) ^ ((dv & 7) << 4))) = (_Float16)xv[e];
        }
      }
    }
    if (tid < BKT) a_s[tid] = a_g[bh * SLEN + j0 + tid];
    __syncthreads();

    // ---- QK^T (split: qh*kh + ql*kh + qh*kl): rows wr*16+, cols wc*32+ ----
    f32x4 sacc[2];
    sacc[0] = z4; sacc[1] = z4;
    #pragma unroll
    for (int ks = 0; ks < 4; ++ks) {
      const int bc = ks * 64 + lg * 16;     // byte col, 16B-aligned
      #pragma unroll
      for (int cf = 0; cf < 2; ++cf) {
        const int krow = wc * 32 + cf * 16 + l15;
        const int sw = (krow & 7) << 4;
        f16x8 bhf = *(const f16x8*)((char*)Ks_hi + krow * 256 + (bc ^ sw));
        f16x8 blf = *(const f16x8*)((char*)Ks_lo + krow * 256 + (bc ^ sw));
        sacc[cf] = __builtin_amdgcn_mfma_f32_16x16x32_f16(qh[ks], bhf, sacc[cf], 0, 0, 0);
        sacc[cf] = __builtin_amdgcn_mfma_f32_16x16x32_f16(ql[ks], bhf, sacc[cf], 0, 0, 0);
        sacc[cf] = __builtin_amdgcn_mfma_f32_16x16x32_f16(qh[ks], blf, sacc[cf], 0, 0, 0);
      }
    }
    // ---- elementwise: decay, causal mask, rowsum partials, C -> LDS ----
    #pragma unroll
    for (int cf = 0; cf < 2; ++cf) {
      const int jj = wc * 32 + cf * 16 + l15;
      const float aj = a_s[jj];
      #pragma unroll
      for (int rr2 = 0; rr2 < 4; ++rr2) {
        const int il = wr * 16 + lg * 4 + rr2;
        const float e = __expf(fminf(aj - ms_reg[rr2], 0.f));
        float val = sacc[cf][rr2] * e;
        if (jj + joff > il) val = 0.f;      // causal mask (diag tile only)
        ps[rr2] += val;
        *(_Float16*)((char*)Cs + il * 128 + ((jj * 2) ^ ((il & 7) << 4))) = (_Float16)val;
      }
    }
    __syncthreads();   // full C tile visible before PV
    // ---- PV (plain fp16): rows wr*16+, dv cols wc*64+{0..63} ----
    #pragma unroll
    for (int ks = 0; ks < 2; ++ks) {
      const int bc = ks * 64 + lg * 16;
      const int crow = wr * 16 + l15;
      f16x8 ca = *(const f16x8*)((char*)Cs + crow * 128 + (bc ^ ((crow & 7) << 4)));
      #pragma unroll
      for (int cf = 0; cf < 4; ++cf) {
        const int vrow = wc * 64 + cf * 16 + l15;
        f16x8 vb = *(const f16x8*)((char*)Vts + vrow * 128 + (bc ^ ((vrow & 7) << 4)));
        hacc[cf] = __builtin_amdgcn_mfma_f32_16x16x32_f16(ca, vb, hacc[cf], 0, 0, 0);
      }
    }
  }

  // ---- rowsum: reduce across 16-lane groups, then the 2 col-wave-groups ----
  #pragma unroll
  for (int rr2 = 0; rr2 < 4; ++rr2) {
    float vsum = ps[rr2];
    #pragma unroll
    for (int m = 1; m < 16; m <<= 1) vsum += __shfl_xor(vsum, m);
    if (l15 == 0) rs_lds[wr * 16 + lg * 4 + rr2][wc] = vsum;
  }
  __syncthreads();
  // ---- finalize: norm = max(|rowsum|, exp(-max_log_D)) + eps; write h ----
  #pragma unroll
  for (int rr2 = 0; rr2 < 4; ++rr2) {
    const int il = wr * 16 + lg * 4 + rr2;
    const float rsum = rs_lds[il][0] + rs_lds[il][1];
    const float inv = 1.0f / (fmaxf(fabsf(rsum), fl_reg[rr2]) + 1e-6f);
    const size_t orow = (size_t)(b * SLEN + i0 + il) * DMODEL + h * DHEAD;
    #pragma unroll
    for (int cf = 0; cf < 4; ++cf)
      out[orow + wc * 64 + cf * 16 + l15] = hacc[cf][rr2] * inv;
  }
}

// ---------------- Kernel 4: in-place LayerNorm on d_out ---------------------
__global__ __launch_bounds__(256)
void ln_kernel(float* __restrict__ out, const float* __restrict__ gamma) {
  const int row = blockIdx.x;
  const int tid = threadIdx.x;
  float* x = out + (size_t)row * DMODEL;
  f32x4 xv = ((const f32x4*)x)[tid];
  float s = xv[0] + xv[1] + xv[2] + xv[3];
  float qq = xv[0] * xv[0] + xv[1] * xv[1] + xv[2] * xv[2] + xv[3] * xv[3];
  #pragma unroll
  for (int m = 1; m < 64; m <<= 1) { s += __shfl_xor(s, m); qq += __shfl_xor(qq, m); }
  __shared__ float ss[4], sq[4];
  const int wid = tid >> 6;
  if ((tid & 63) == 0) { ss[wid] = s; sq[wid] = qq; }
  __syncthreads();
  s = ss[0] + ss[1] + ss[2] + ss[3];
  qq = sq[0] + sq[1] + sq[2] + sq[3];
  const float mu = s * (1.f / 1024.f);
  const float var = qq * (1.f / 1024.f) - mu * mu;
  const float rstd = rsqrtf(var + 1e-5f);
  f32x4 g = ((const f32x4*)gamma)[tid];
  f32x4 ov;
  ov[0] = (xv[0] - mu) * rstd * g[0];
  ov[1] = (xv[1] - mu) * rstd * g[1];
  ov[2] = (xv[2] - mu) * rstd * g[2];
  ov[3] = (xv[3] - mu) * rstd * g[3];
  ((f32x4*)x)[tid] = ov;
}

extern "C" void kernel_launch(void* const* d_in, const int* in_sizes, int n_in,
                              void* d_out, int out_size, void* d_ws, size_t ws_size,
                              hipStream_t stream) {
  (void)in_sizes; (void)n_in; (void)out_size; (void)ws_size;
  const float* q   = (const float*)d_in[0];
  const float* k   = (const float*)d_in[1];
  const float* v   = (const float*)d_in[2];
  const float* igw = (const float*)d_in[3];
  const float* igb = (const float*)d_in[4];
  const float* fgw = (const float*)d_in[5];
  const float* fgb = (const float*)d_in[6];
  const float* lns = (const float*)d_in[7];
  float* out = (float*)d_out;

  float* gpre = (float*)d_ws;            // [16][4096]
  float* a_g  = gpre + 16 * 4096;        // [16][2048]
  float* ms_g = a_g + 16 * 2048;         // [16][2048]
  float* fl_g = ms_g + 16 * 2048;        // [16][2048]

  gates_kernel<<<dim3(256), dim3(256), 0, stream>>>(q, k, v, igw, fgw, gpre);
  scan_kernel<<<dim3(16), dim3(256), 0, stream>>>(gpre, igb, fgb, a_g, ms_g, fl_g);
  mlstm_main<<<dim3(512), dim3(512), 0, stream>>>(q, k, v, a_g, ms_g, fl_g, out);
  ln_kernel<<<dim3(4096), dim3(256), 0, stream>>>(out, lns);
}

// Round 6
// 221.057 us; speedup vs baseline: 1.0341x; 1.0163x over previous
//
#include <hip/hip_runtime.h>
#include <hip/hip_bf16.h>

#define SLEN 2048
#define DMODEL 1024
#define NHEAD 8
#define DHEAD 128
#define BM 64
#define BKT 64
#define QSCALE 0.08838834764831845f  // 1/sqrt(128)

typedef __attribute__((ext_vector_type(4))) float f32x4;
typedef __attribute__((ext_vector_type(8))) _Float16 f16x8;
typedef __attribute__((ext_vector_type(4))) _Float16 f16x4;

// ---------------- Kernel 1: gate preactivations (ILP-heavy) -----------------
// gpre[g][row], g 0..7 = ig head g, 8..15 = fg head g-8; row = b*2048+s (4096)
// 1024 blocks x 4 rows. Thread owns c-slice [tid*4, tid*4+4) per 1024-seg.
// 64 independent accumulators/thread -> 60 independent 16B loads in flight.
__global__ __launch_bounds__(256)
void gates_kernel(const float* __restrict__ q, const float* __restrict__ k,
                  const float* __restrict__ v, const float* __restrict__ igw,
                  const float* __restrict__ fgw, float* __restrict__ gpre) {
  const int row0 = blockIdx.x * 4;
  const int tid = threadIdx.x;
  const int lane = tid & 63, wid = tid >> 6;
  const int c4 = tid * 4;
  float acc[64];
  #pragma unroll
  for (int i = 0; i < 64; ++i) acc[i] = 0.f;
  const float* srcs[3] = {q, k, v};
  #pragma unroll
  for (int seg = 0; seg < 3; ++seg) {
    const float* src = srcs[seg];
    f32x4 xv[4];
    #pragma unroll
    for (int r = 0; r < 4; ++r)
      xv[r] = *(const f32x4*)(src + (size_t)(row0 + r) * 1024 + c4);
    #pragma unroll
    for (int g = 0; g < 8; ++g) {
      f32x4 wi = *(const f32x4*)(igw + (size_t)g * 3072 + seg * 1024 + c4);
      f32x4 wf = *(const f32x4*)(fgw + (size_t)g * 3072 + seg * 1024 + c4);
      #pragma unroll
      for (int r = 0; r < 4; ++r) {
        acc[r * 16 + g]     += xv[r][0] * wi[0] + xv[r][1] * wi[1]
                             + xv[r][2] * wi[2] + xv[r][3] * wi[3];
        acc[r * 16 + 8 + g] += xv[r][0] * wf[0] + xv[r][1] * wf[1]
                             + xv[r][2] * wf[2] + xv[r][3] * wf[3];
      }
    }
  }
  // reduce: 4 DPP levels (intra-16) -> LDS partials [wave][acc][group] -> 64 thr
  __shared__ float red[4][64][4];
  #pragma unroll
  for (int i = 0; i < 64; ++i) {
    float s = acc[i];
    #pragma unroll
    for (int m = 1; m < 16; m <<= 1) s += __shfl_xor(s, m);
    if ((lane & 15) == 0) red[wid][i][lane >> 4] = s;
  }
  __syncthreads();
  if (tid < 64) {
    float s = 0.f;
    #pragma unroll
    for (int w = 0; w < 4; ++w) {
      f32x4 p = *(const f32x4*)&red[w][tid][0];
      s += p[0] + p[1] + p[2] + p[3];
    }
    const int r = tid >> 4, g = tid & 15;
    gpre[(size_t)g * 4096 + row0 + r] = s;
  }
}

// ---------------- Kernel 2: per-(b,h) scans (serial, obviously correct) -----
__global__ __launch_bounds__(256)
void scan_kernel(const float* __restrict__ gpre, const float* __restrict__ igb,
                 const float* __restrict__ fgb, float* __restrict__ a_out,
                 float* __restrict__ ms_out, float* __restrict__ fl_out) {
  const int bh = blockIdx.x;            // b*8 + h
  const int h = bh & 7;
  const int b = bh >> 3;
  const int tid = threadIdx.x;
  __shared__ double sbd[256];
  __shared__ float sbf[256];
  const int base = b * 2048 + tid * 8;
  const float ig_b = igb[h], fg_b = fgb[h];
  double cs[8];
  float av[8];
  double tot = 0.0;
  #pragma unroll
  for (int e = 0; e < 8; ++e) {
    float x = gpre[(size_t)(8 + h) * 4096 + base + e] + fg_b;
    float l = fminf(x, 0.f) - log1pf(__expf(-fabsf(x)));   // log_sigmoid
    tot += (double)l;
    cs[e] = tot;
  }
  sbd[tid] = tot;
  __syncthreads();
  if (tid == 0) {
    double run = 0.0;
    for (int i = 0; i < 256; ++i) { double t2 = sbd[i]; sbd[i] = run; run += t2; }
  }
  __syncthreads();
  const double excl = sbd[tid];
  float mtot = -3.4e38f;
  #pragma unroll
  for (int e = 0; e < 8; ++e) {
    cs[e] += excl;
    float ig = gpre[(size_t)h * 4096 + base + e] + ig_b;
    av[e] = (float)((double)ig - cs[e]);
    mtot = fmaxf(mtot, av[e]);
  }
  sbf[tid] = mtot;
  __syncthreads();
  if (tid == 0) {
    float run = -3.4e38f;
    for (int i = 0; i < 256; ++i) { float t2 = sbf[i]; sbf[i] = run; run = fmaxf(run, t2); }
  }
  __syncthreads();
  float run = sbf[tid];
  const int obase = bh * 2048 + tid * 8;
  #pragma unroll
  for (int e = 0; e < 8; ++e) {
    run = fmaxf(run, av[e]);
    a_out[obase + e] = av[e];
    ms_out[obase + e] = run;
    fl_out[obase + e] = __expf(-(float)(cs[e] + (double)run));  // exp(-max_log_D)
  }
}

// ---------------- Kernel 3: main causal mLSTM (fp16 split QK, plain PV) -----
// grid 512: heavy half (t=31..16) first, light half after. 8 waves = 4r x 2c.
// LDS XOR-swizzled (byte ^= (row&7)<<4). T14: next-tile K/V/a prefetched into
// registers during compute; staging ds_write has data already in flight.
__global__ __launch_bounds__(512, 4)
void mlstm_main(const float* __restrict__ q, const float* __restrict__ k,
                const float* __restrict__ v, const float* __restrict__ a_g,
                const float* __restrict__ ms_g, const float* __restrict__ fl_g,
                float* __restrict__ out) {
  __shared__ __align__(16) _Float16 Ks_hi[BKT * 128];   // [64][128], 256B rows
  __shared__ __align__(16) _Float16 Ks_lo[BKT * 128];
  __shared__ __align__(16) _Float16 Vts[DHEAD * BKT];   // [dv 128][j 64], 128B rows
  __shared__ __align__(16) _Float16 Cs[BM * BKT];       // [i 64][j 64], 128B rows
  __shared__ float a_s[BKT];
  __shared__ float rs_lds[BM][2];

  const int bid = blockIdx.x;
  int t, bh;
  if (bid < 256) { t = 31 - (bid >> 4); bh = bid & 15; }      // heavy first
  else           { t = (bid - 256) >> 4; bh = (bid - 256) & 15; }
  const int b = bh >> 3, h = bh & 7;
  const int i0 = t * BM;
  const int tid = threadIdx.x;
  const int lane = tid & 63;
  const int wid = tid >> 6;
  const int wr = wid >> 1;      // row group 0..3 (16 rows each)
  const int wc = wid & 1;       // col group 0..1
  const int l15 = lane & 15;
  const int lg = lane >> 4;

  const f32x4 z4 = {0.f, 0.f, 0.f, 0.f};

  // ---- Q fragments to registers (QSCALE folded, hi/lo split) ----
  f16x8 qh[4], ql[4];
  {
    const float* qbase = q + (size_t)(b * SLEN + i0 + wr * 16 + l15) * DMODEL + h * DHEAD;
    #pragma unroll
    for (int ks = 0; ks < 4; ++ks) {
      f32x4 x0 = *(const f32x4*)(qbase + ks * 32 + lg * 8);
      f32x4 x1 = *(const f32x4*)(qbase + ks * 32 + lg * 8 + 4);
      f16x8 hi, lo;
      #pragma unroll
      for (int e = 0; e < 4; ++e) {
        float s0 = x0[e] * QSCALE, s1 = x1[e] * QSCALE;
        _Float16 h0 = (_Float16)s0, h1 = (_Float16)s1;
        hi[e] = h0;     hi[e + 4] = h1;
        lo[e] = (_Float16)(s0 - (float)h0);
        lo[e + 4] = (_Float16)(s1 - (float)h1);
      }
      qh[ks] = hi; ql[ks] = lo;
    }
  }

  float ms_reg[4], fl_reg[4];
  {
    const float* mp = ms_g + bh * SLEN + i0 + wr * 16;
    const float* fp = fl_g + bh * SLEN + i0 + wr * 16;
    #pragma unroll
    for (int rr2 = 0; rr2 < 4; ++rr2) {
      ms_reg[rr2] = mp[lg * 4 + rr2];
      fl_reg[rr2] = fp[lg * 4 + rr2];
    }
  }

  // prefetch-state registers (T14)
  const int krow = tid >> 3;              // 0..63
  const int kc0 = (tid & 7) * 16;         // K col chunk
  const int vj = tid & 63;                // V source row j
  const int vgrp = tid >> 6;              // 0..7
  f32x4 kpre[4], vpre[4];
  float apre = 0.f;

  // issue prefetch for tile jt
#define PREFETCH(JT_) do {                                                      \
    const int j0_ = (JT_) * BKT;                                                \
    const float* kp_ = k + (size_t)(b * SLEN + j0_ + krow) * DMODEL + h * DHEAD + kc0; \
    _Pragma("unroll")                                                           \
    for (int e = 0; e < 4; ++e) kpre[e] = *(const f32x4*)(kp_ + e * 4);         \
    const float* vp_ = v + (size_t)(b * SLEN + j0_ + vj) * DMODEL + h * DHEAD;  \
    _Pragma("unroll")                                                           \
    for (int c = 0; c < 4; ++c) vpre[c] = *(const f32x4*)(vp_ + vgrp * 16 + c * 4); \
    if (tid < BKT) apre = a_g[bh * SLEN + j0_ + tid];                           \
  } while (0)

  f32x4 hacc[4];
  #pragma unroll
  for (int a2 = 0; a2 < 4; ++a2) hacc[a2] = z4;
  float ps[4] = {0.f, 0.f, 0.f, 0.f};

  PREFETCH(0);

  for (int jt = 0; jt <= t; ++jt) {
    const int joff = jt * BKT - i0;   // mask col jj iff jj + joff > il
    __syncthreads();                  // prev iteration's LDS reads complete
    // ---- stage K tile hi/lo from kpre (swizzled) ----
    {
      char* bh_ = (char*)Ks_hi + krow * 256;
      char* bl_ = (char*)Ks_lo + krow * 256;
      const int sw = (krow & 7) << 4;
      #pragma unroll
      for (int e = 0; e < 4; ++e) {
        f32x4 xv = kpre[e];
        f16x4 hi, lo;
        #pragma unroll
        for (int u = 0; u < 4; ++u) {
          _Float16 hh = (_Float16)xv[u];
          hi[u] = hh; lo[u] = (_Float16)(xv[u] - (float)hh);
        }
        const int bc = (kc0 + e * 4) * 2;    // 8B-aligned byte col
        *(f16x4*)(bh_ + (bc ^ sw)) = hi;
        *(f16x4*)(bl_ + (bc ^ sw)) = lo;
      }
    }
    // ---- stage V transposed from vpre: Vts[dv][j] ----
    {
      #pragma unroll
      for (int c = 0; c < 4; ++c) {
        const int dv0 = vgrp * 16 + c * 4;
        f32x4 xv = vpre[c];
        #pragma unroll
        for (int e = 0; e < 4; ++e) {
          const int dv = dv0 + e;
          *(_Float16*)((char*)Vts + dv * 128 + ((vj * 2) ^ ((dv & 7) << 4))) = (_Float16)xv[e];
        }
      }
    }
    if (tid < BKT) a_s[tid] = apre;
    __syncthreads();

    // issue next tile's loads now; latency hides under QK+elem+PV
    {
      const int jn = (jt < t) ? (jt + 1) : t;
      PREFETCH(jn);
    }

    // ---- QK^T (split: qh*kh + ql*kh + qh*kl): rows wr*16+, cols wc*32+ ----
    f32x4 sacc[2];
    sacc[0] = z4; sacc[1] = z4;
    #pragma unroll
    for (int ks = 0; ks < 4; ++ks) {
      const int bc = ks * 64 + lg * 16;     // byte col, 16B-aligned
      #pragma unroll
      for (int cf = 0; cf < 2; ++cf) {
        const int krw = wc * 32 + cf * 16 + l15;
        const int sw = (krw & 7) << 4;
        f16x8 bhf = *(const f16x8*)((char*)Ks_hi + krw * 256 + (bc ^ sw));
        f16x8 blf = *(const f16x8*)((char*)Ks_lo + krw * 256 + (bc ^ sw));
        sacc[cf] = __builtin_amdgcn_mfma_f32_16x16x32_f16(qh[ks], bhf, sacc[cf], 0, 0, 0);
        sacc[cf] = __builtin_amdgcn_mfma_f32_16x16x32_f16(ql[ks], bhf, sacc[cf], 0, 0, 0);
        sacc[cf] = __builtin_amdgcn_mfma_f32_16x16x32_f16(qh[ks], blf, sacc[cf], 0, 0, 0);
      }
    }
    // ---- elementwise: decay, causal mask, rowsum partials, C -> LDS ----
    #pragma unroll
    for (int cf = 0; cf < 2; ++cf) {
      const int jj = wc * 32 + cf * 16 + l15;
      const float aj = a_s[jj];
      #pragma unroll
      for (int rr2 = 0; rr2 < 4; ++rr2) {
        const int il = wr * 16 + lg * 4 + rr2;
        const float e = __expf(fminf(aj - ms_reg[rr2], 0.f));
        float val = sacc[cf][rr2] * e;
        if (jj + joff > il) val = 0.f;      // causal mask (diag tile only)
        ps[rr2] += val;
        *(_Float16*)((char*)Cs + il * 128 + ((jj * 2) ^ ((il & 7) << 4))) = (_Float16)val;
      }
    }
    __syncthreads();   // full C tile visible before PV
    // ---- PV (plain fp16): rows wr*16+, dv cols wc*64+{0..63} ----
    #pragma unroll
    for (int ks = 0; ks < 2; ++ks) {
      const int bc = ks * 64 + lg * 16;
      const int crow = wr * 16 + l15;
      f16x8 ca = *(const f16x8*)((char*)Cs + crow * 128 + (bc ^ ((crow & 7) << 4)));
      #pragma unroll
      for (int cf = 0; cf < 4; ++cf) {
        const int vrow = wc * 64 + cf * 16 + l15;
        f16x8 vb = *(const f16x8*)((char*)Vts + vrow * 128 + (bc ^ ((vrow & 7) << 4)));
        hacc[cf] = __builtin_amdgcn_mfma_f32_16x16x32_f16(ca, vb, hacc[cf], 0, 0, 0);
      }
    }
  }
#undef PREFETCH

  // ---- rowsum: reduce across 16-lane groups, then the 2 col-wave-groups ----
  #pragma unroll
  for (int rr2 = 0; rr2 < 4; ++rr2) {
    float vsum = ps[rr2];
    #pragma unroll
    for (int m = 1; m < 16; m <<= 1) vsum += __shfl_xor(vsum, m);
    if (l15 == 0) rs_lds[wr * 16 + lg * 4 + rr2][wc] = vsum;
  }
  __syncthreads();
  // ---- finalize: norm = max(|rowsum|, exp(-max_log_D)) + eps; write h ----
  #pragma unroll
  for (int rr2 = 0; rr2 < 4; ++rr2) {
    const int il = wr * 16 + lg * 4 + rr2;
    const float rsum = rs_lds[il][0] + rs_lds[il][1];
    const float inv = 1.0f / (fmaxf(fabsf(rsum), fl_reg[rr2]) + 1e-6f);
    const size_t orow = (size_t)(b * SLEN + i0 + il) * DMODEL + h * DHEAD;
    #pragma unroll
    for (int cf = 0; cf < 4; ++cf)
      out[orow + wc * 64 + cf * 16 + l15] = hacc[cf][rr2] * inv;
  }
}

// ---------------- Kernel 4: in-place LayerNorm on d_out ---------------------
__global__ __launch_bounds__(256)
void ln_kernel(float* __restrict__ out, const float* __restrict__ gamma) {
  const int row = blockIdx.x;
  const int tid = threadIdx.x;
  float* x = out + (size_t)row * DMODEL;
  f32x4 xv = ((const f32x4*)x)[tid];
  float s = xv[0] + xv[1] + xv[2] + xv[3];
  float qq = xv[0] * xv[0] + xv[1] * xv[1] + xv[2] * xv[2] + xv[3] * xv[3];
  #pragma unroll
  for (int m = 1; m < 64; m <<= 1) { s += __shfl_xor(s, m); qq += __shfl_xor(qq, m); }
  __shared__ float ss[4], sq[4];
  const int wid = tid >> 6;
  if ((tid & 63) == 0) { ss[wid] = s; sq[wid] = qq; }
  __syncthreads();
  s = ss[0] + ss[1] + ss[2] + ss[3];
  qq = sq[0] + sq[1] + sq[2] + sq[3];
  const float mu = s * (1.f / 1024.f);
  const float var = qq * (1.f / 1024.f) - mu * mu;
  const float rstd = rsqrtf(var + 1e-5f);
  f32x4 g = ((const f32x4*)gamma)[tid];
  f32x4 ov;
  ov[0] = (xv[0] - mu) * rstd * g[0];
  ov[1] = (xv[1] - mu) * rstd * g[1];
  ov[2] = (xv[2] - mu) * rstd * g[2];
  ov[3] = (xv[3] - mu) * rstd * g[3];
  ((f32x4*)x)[tid] = ov;
}

extern "C" void kernel_launch(void* const* d_in, const int* in_sizes, int n_in,
                              void* d_out, int out_size, void* d_ws, size_t ws_size,
                              hipStream_t stream) {
  (void)in_sizes; (void)n_in; (void)out_size; (void)ws_size;
  const float* q   = (const float*)d_in[0];
  const float* k   = (const float*)d_in[1];
  const float* v   = (const float*)d_in[2];
  const float* igw = (const float*)d_in[3];
  const float* igb = (const float*)d_in[4];
  const float* fgw = (const float*)d_in[5];
  const float* fgb = (const float*)d_in[6];
  const float* lns = (const float*)d_in[7];
  float* out = (float*)d_out;

  float* gpre = (float*)d_ws;            // [16][4096]
  float* a_g  = gpre + 16 * 4096;        // [16][2048]
  float* ms_g = a_g + 16 * 2048;         // [16][2048]
  float* fl_g = ms_g + 16 * 2048;        // [16][2048]

  gates_kernel<<<dim3(1024), dim3(256), 0, stream>>>(q, k, v, igw, fgw, gpre);
  scan_kernel<<<dim3(16), dim3(256), 0, stream>>>(gpre, igb, fgb, a_g, ms_g, fl_g);
  mlstm_main<<<dim3(512), dim3(512), 0, stream>>>(q, k, v, a_g, ms_g, fl_g, out);
  ln_kernel<<<dim3(4096), dim3(256), 0, stream>>>(out, lns);
}

// Round 7
// 165.602 us; speedup vs baseline: 1.3804x; 1.3349x over previous
//
#include <hip/hip_runtime.h>
#include <hip/hip_bf16.h>

#define SLEN 2048
#define DMODEL 1024
#define NHEAD 8
#define DHEAD 128
#define BM 64
#define BKT 64
#define QSCALE 0.08838834764831845f  // 1/sqrt(128)

typedef __attribute__((ext_vector_type(4))) float f32x4;
typedef __attribute__((ext_vector_type(8))) _Float16 f16x8;
typedef __attribute__((ext_vector_type(4))) _Float16 f16x4;

// ---------------- Kernel 1: gate preactivations (ILP-heavy) -----------------
// gpre[g][row], g 0..7 = ig head g, 8..15 = fg head g-8; row = b*2048+s (4096)
// 1024 blocks x 4 rows. Thread owns c-slice [tid*4, tid*4+4) per 1024-seg.
// 64 independent accumulators/thread -> 60 independent 16B loads in flight.
__global__ __launch_bounds__(256)
void gates_kernel(const float* __restrict__ q, const float* __restrict__ k,
                  const float* __restrict__ v, const float* __restrict__ igw,
                  const float* __restrict__ fgw, float* __restrict__ gpre) {
  const int row0 = blockIdx.x * 4;
  const int tid = threadIdx.x;
  const int lane = tid & 63, wid = tid >> 6;
  const int c4 = tid * 4;
  float acc[64];
  #pragma unroll
  for (int i = 0; i < 64; ++i) acc[i] = 0.f;
  const float* srcs[3] = {q, k, v};
  #pragma unroll
  for (int seg = 0; seg < 3; ++seg) {
    const float* src = srcs[seg];
    f32x4 xv[4];
    #pragma unroll
    for (int r = 0; r < 4; ++r)
      xv[r] = *(const f32x4*)(src + (size_t)(row0 + r) * 1024 + c4);
    #pragma unroll
    for (int g = 0; g < 8; ++g) {
      f32x4 wi = *(const f32x4*)(igw + (size_t)g * 3072 + seg * 1024 + c4);
      f32x4 wf = *(const f32x4*)(fgw + (size_t)g * 3072 + seg * 1024 + c4);
      #pragma unroll
      for (int r = 0; r < 4; ++r) {
        acc[r * 16 + g]     += xv[r][0] * wi[0] + xv[r][1] * wi[1]
                             + xv[r][2] * wi[2] + xv[r][3] * wi[3];
        acc[r * 16 + 8 + g] += xv[r][0] * wf[0] + xv[r][1] * wf[1]
                             + xv[r][2] * wf[2] + xv[r][3] * wf[3];
      }
    }
  }
  // reduce: 4 DPP levels (intra-16) -> LDS partials [wave][acc][group] -> 64 thr
  __shared__ float red[4][64][4];
  #pragma unroll
  for (int i = 0; i < 64; ++i) {
    float s = acc[i];
    #pragma unroll
    for (int m = 1; m < 16; m <<= 1) s += __shfl_xor(s, m);
    if ((lane & 15) == 0) red[wid][i][lane >> 4] = s;
  }
  __syncthreads();
  if (tid < 64) {
    float s = 0.f;
    #pragma unroll
    for (int w = 0; w < 4; ++w) {
      f32x4 p = *(const f32x4*)&red[w][tid][0];
      s += p[0] + p[1] + p[2] + p[3];
    }
    const int r = tid >> 4, g = tid & 15;
    gpre[(size_t)g * 4096 + row0 + r] = s;
  }
}

// ---------------- Kernel 2: per-(b,h) scans (serial, obviously correct) -----
__global__ __launch_bounds__(256)
void scan_kernel(const float* __restrict__ gpre, const float* __restrict__ igb,
                 const float* __restrict__ fgb, float* __restrict__ a_out,
                 float* __restrict__ ms_out, float* __restrict__ fl_out) {
  const int bh = blockIdx.x;            // b*8 + h
  const int h = bh & 7;
  const int b = bh >> 3;
  const int tid = threadIdx.x;
  __shared__ double sbd[256];
  __shared__ float sbf[256];
  const int base = b * 2048 + tid * 8;
  const float ig_b = igb[h], fg_b = fgb[h];
  double cs[8];
  float av[8];
  double tot = 0.0;
  #pragma unroll
  for (int e = 0; e < 8; ++e) {
    float x = gpre[(size_t)(8 + h) * 4096 + base + e] + fg_b;
    float l = fminf(x, 0.f) - log1pf(__expf(-fabsf(x)));   // log_sigmoid
    tot += (double)l;
    cs[e] = tot;
  }
  sbd[tid] = tot;
  __syncthreads();
  if (tid == 0) {
    double run = 0.0;
    for (int i = 0; i < 256; ++i) { double t2 = sbd[i]; sbd[i] = run; run += t2; }
  }
  __syncthreads();
  const double excl = sbd[tid];
  float mtot = -3.4e38f;
  #pragma unroll
  for (int e = 0; e < 8; ++e) {
    cs[e] += excl;
    float ig = gpre[(size_t)h * 4096 + base + e] + ig_b;
    av[e] = (float)((double)ig - cs[e]);
    mtot = fmaxf(mtot, av[e]);
  }
  sbf[tid] = mtot;
  __syncthreads();
  if (tid == 0) {
    float run = -3.4e38f;
    for (int i = 0; i < 256; ++i) { float t2 = sbf[i]; sbf[i] = run; run = fmaxf(run, t2); }
  }
  __syncthreads();
  float run = sbf[tid];
  const int obase = bh * 2048 + tid * 8;
  #pragma unroll
  for (int e = 0; e < 8; ++e) {
    run = fmaxf(run, av[e]);
    a_out[obase + e] = av[e];
    ms_out[obase + e] = run;
    fl_out[obase + e] = __expf(-(float)(cs[e] + (double)run));  // exp(-max_log_D)
  }
}

// ---------------- Kernel 3: main causal mLSTM (fp16 split QK, plain PV) -----
// grid 512: heavy half (t=31..16) first, light half after. 8 waves = 4r x 2c.
// LDS XOR-swizzled (byte ^= (row&7)<<4). T14: next-tile K/V/a prefetched into
// registers during compute. NO min-waves bound: occupancy is LDS-capped at
// 2 blocks/CU; pinning the VGPR budget caused scratch spill (R6: WRITE_SIZE
// 16.4->55.9MB, 178us). Let the allocator take ~100 VGPRs.
__global__ __launch_bounds__(512)
void mlstm_main(const float* __restrict__ q, const float* __restrict__ k,
                const float* __restrict__ v, const float* __restrict__ a_g,
                const float* __restrict__ ms_g, const float* __restrict__ fl_g,
                float* __restrict__ out) {
  __shared__ __align__(16) _Float16 Ks_hi[BKT * 128];   // [64][128], 256B rows
  __shared__ __align__(16) _Float16 Ks_lo[BKT * 128];
  __shared__ __align__(16) _Float16 Vts[DHEAD * BKT];   // [dv 128][j 64], 128B rows
  __shared__ __align__(16) _Float16 Cs[BM * BKT];       // [i 64][j 64], 128B rows
  __shared__ float a_s[BKT];
  __shared__ float rs_lds[BM][2];

  const int bid = blockIdx.x;
  int t, bh;
  if (bid < 256) { t = 31 - (bid >> 4); bh = bid & 15; }      // heavy first
  else           { t = (bid - 256) >> 4; bh = (bid - 256) & 15; }
  const int b = bh >> 3, h = bh & 7;
  const int i0 = t * BM;
  const int tid = threadIdx.x;
  const int lane = tid & 63;
  const int wid = tid >> 6;
  const int wr = wid >> 1;      // row group 0..3 (16 rows each)
  const int wc = wid & 1;       // col group 0..1
  const int l15 = lane & 15;
  const int lg = lane >> 4;

  const f32x4 z4 = {0.f, 0.f, 0.f, 0.f};

  // ---- Q fragments to registers (QSCALE folded, hi/lo split) ----
  f16x8 qh[4], ql[4];
  {
    const float* qbase = q + (size_t)(b * SLEN + i0 + wr * 16 + l15) * DMODEL + h * DHEAD;
    #pragma unroll
    for (int ks = 0; ks < 4; ++ks) {
      f32x4 x0 = *(const f32x4*)(qbase + ks * 32 + lg * 8);
      f32x4 x1 = *(const f32x4*)(qbase + ks * 32 + lg * 8 + 4);
      f16x8 hi, lo;
      #pragma unroll
      for (int e = 0; e < 4; ++e) {
        float s0 = x0[e] * QSCALE, s1 = x1[e] * QSCALE;
        _Float16 h0 = (_Float16)s0, h1 = (_Float16)s1;
        hi[e] = h0;     hi[e + 4] = h1;
        lo[e] = (_Float16)(s0 - (float)h0);
        lo[e + 4] = (_Float16)(s1 - (float)h1);
      }
      qh[ks] = hi; ql[ks] = lo;
    }
  }

  float ms_reg[4], fl_reg[4];
  {
    const float* mp = ms_g + bh * SLEN + i0 + wr * 16;
    const float* fp = fl_g + bh * SLEN + i0 + wr * 16;
    #pragma unroll
    for (int rr2 = 0; rr2 < 4; ++rr2) {
      ms_reg[rr2] = mp[lg * 4 + rr2];
      fl_reg[rr2] = fp[lg * 4 + rr2];
    }
  }

  // prefetch-state registers (T14)
  const int krow = tid >> 3;              // 0..63
  const int kc0 = (tid & 7) * 16;         // K col chunk
  const int vj = tid & 63;                // V source row j
  const int vgrp = tid >> 6;              // 0..7
  f32x4 kpre[4], vpre[4];
  float apre = 0.f;

  // issue prefetch for tile jt
#define PREFETCH(JT_) do {                                                      \
    const int j0_ = (JT_) * BKT;                                                \
    const float* kp_ = k + (size_t)(b * SLEN + j0_ + krow) * DMODEL + h * DHEAD + kc0; \
    _Pragma("unroll")                                                           \
    for (int e = 0; e < 4; ++e) kpre[e] = *(const f32x4*)(kp_ + e * 4);         \
    const float* vp_ = v + (size_t)(b * SLEN + j0_ + vj) * DMODEL + h * DHEAD;  \
    _Pragma("unroll")                                                           \
    for (int c = 0; c < 4; ++c) vpre[c] = *(const f32x4*)(vp_ + vgrp * 16 + c * 4); \
    if (tid < BKT) apre = a_g[bh * SLEN + j0_ + tid];                           \
  } while (0)

  f32x4 hacc[4];
  #pragma unroll
  for (int a2 = 0; a2 < 4; ++a2) hacc[a2] = z4;
  float ps[4] = {0.f, 0.f, 0.f, 0.f};

  PREFETCH(0);

  for (int jt = 0; jt <= t; ++jt) {
    const int joff = jt * BKT - i0;   // mask col jj iff jj + joff > il
    __syncthreads();                  // prev iteration's LDS reads complete
    // ---- stage K tile hi/lo from kpre (swizzled) ----
    {
      char* bh_ = (char*)Ks_hi + krow * 256;
      char* bl_ = (char*)Ks_lo + krow * 256;
      const int sw = (krow & 7) << 4;
      #pragma unroll
      for (int e = 0; e < 4; ++e) {
        f32x4 xv = kpre[e];
        f16x4 hi, lo;
        #pragma unroll
        for (int u = 0; u < 4; ++u) {
          _Float16 hh = (_Float16)xv[u];
          hi[u] = hh; lo[u] = (_Float16)(xv[u] - (float)hh);
        }
        const int bc = (kc0 + e * 4) * 2;    // 8B-aligned byte col
        *(f16x4*)(bh_ + (bc ^ sw)) = hi;
        *(f16x4*)(bl_ + (bc ^ sw)) = lo;
      }
    }
    // ---- stage V transposed from vpre: Vts[dv][j] ----
    {
      #pragma unroll
      for (int c = 0; c < 4; ++c) {
        const int dv0 = vgrp * 16 + c * 4;
        f32x4 xv = vpre[c];
        #pragma unroll
        for (int e = 0; e < 4; ++e) {
          const int dv = dv0 + e;
          *(_Float16*)((char*)Vts + dv * 128 + ((vj * 2) ^ ((dv & 7) << 4))) = (_Float16)xv[e];
        }
      }
    }
    if (tid < BKT) a_s[tid] = apre;
    __syncthreads();

    // issue next tile's loads now; latency hides under QK+elem+PV
    if (jt < t) PREFETCH(jt + 1);

    // ---- QK^T (split: qh*kh + ql*kh + qh*kl): rows wr*16+, cols wc*32+ ----
    f32x4 sacc[2];
    sacc[0] = z4; sacc[1] = z4;
    #pragma unroll
    for (int ks = 0; ks < 4; ++ks) {
      const int bc = ks * 64 + lg * 16;     // byte col, 16B-aligned
      #pragma unroll
      for (int cf = 0; cf < 2; ++cf) {
        const int krw = wc * 32 + cf * 16 + l15;
        const int sw = (krw & 7) << 4;
        f16x8 bhf = *(const f16x8*)((char*)Ks_hi + krw * 256 + (bc ^ sw));
        f16x8 blf = *(const f16x8*)((char*)Ks_lo + krw * 256 + (bc ^ sw));
        sacc[cf] = __builtin_amdgcn_mfma_f32_16x16x32_f16(qh[ks], bhf, sacc[cf], 0, 0, 0);
        sacc[cf] = __builtin_amdgcn_mfma_f32_16x16x32_f16(ql[ks], bhf, sacc[cf], 0, 0, 0);
        sacc[cf] = __builtin_amdgcn_mfma_f32_16x16x32_f16(qh[ks], blf, sacc[cf], 0, 0, 0);
      }
    }
    // ---- elementwise: decay, causal mask, rowsum partials, C -> LDS ----
    #pragma unroll
    for (int cf = 0; cf < 2; ++cf) {
      const int jj = wc * 32 + cf * 16 + l15;
      const float aj = a_s[jj];
      #pragma unroll
      for (int rr2 = 0; rr2 < 4; ++rr2) {
        const int il = wr * 16 + lg * 4 + rr2;
        const float e = __expf(fminf(aj - ms_reg[rr2], 0.f));
        float val = sacc[cf][rr2] * e;
        if (jj + joff > il) val = 0.f;      // causal mask (diag tile only)
        ps[rr2] += val;
        *(_Float16*)((char*)Cs + il * 128 + ((jj * 2) ^ ((il & 7) << 4))) = (_Float16)val;
      }
    }
    __syncthreads();   // full C tile visible before PV
    // ---- PV (plain fp16): rows wr*16+, dv cols wc*64+{0..63} ----
    #pragma unroll
    for (int ks = 0; ks < 2; ++ks) {
      const int bc = ks * 64 + lg * 16;
      const int crow = wr * 16 + l15;
      f16x8 ca = *(const f16x8*)((char*)Cs + crow * 128 + (bc ^ ((crow & 7) << 4)));
      #pragma unroll
      for (int cf = 0; cf < 4; ++cf) {
        const int vrow = wc * 64 + cf * 16 + l15;
        f16x8 vb = *(const f16x8*)((char*)Vts + vrow * 128 + (bc ^ ((vrow & 7) << 4)));
        hacc[cf] = __builtin_amdgcn_mfma_f32_16x16x32_f16(ca, vb, hacc[cf], 0, 0, 0);
      }
    }
  }
#undef PREFETCH

  // ---- rowsum: reduce across 16-lane groups, then the 2 col-wave-groups ----
  #pragma unroll
  for (int rr2 = 0; rr2 < 4; ++rr2) {
    float vsum = ps[rr2];
    #pragma unroll
    for (int m = 1; m < 16; m <<= 1) vsum += __shfl_xor(vsum, m);
    if (l15 == 0) rs_lds[wr * 16 + lg * 4 + rr2][wc] = vsum;
  }
  __syncthreads();
  // ---- finalize: norm = max(|rowsum|, exp(-max_log_D)) + eps; write h ----
  #pragma unroll
  for (int rr2 = 0; rr2 < 4; ++rr2) {
    const int il = wr * 16 + lg * 4 + rr2;
    const float rsum = rs_lds[il][0] + rs_lds[il][1];
    const float inv = 1.0f / (fmaxf(fabsf(rsum), fl_reg[rr2]) + 1e-6f);
    const size_t orow = (size_t)(b * SLEN + i0 + il) * DMODEL + h * DHEAD;
    #pragma unroll
    for (int cf = 0; cf < 4; ++cf)
      out[orow + wc * 64 + cf * 16 + l15] = hacc[cf][rr2] * inv;
  }
}

// ---------------- Kernel 4: in-place LayerNorm on d_out ---------------------
__global__ __launch_bounds__(256)
void ln_kernel(float* __restrict__ out, const float* __restrict__ gamma) {
  const int row = blockIdx.x;
  const int tid = threadIdx.x;
  float* x = out + (size_t)row * DMODEL;
  f32x4 xv = ((const f32x4*)x)[tid];
  float s = xv[0] + xv[1] + xv[2] + xv[3];
  float qq = xv[0] * xv[0] + xv[1] * xv[1] + xv[2] * xv[2] + xv[3] * xv[3];
  #pragma unroll
  for (int m = 1; m < 64; m <<= 1) { s += __shfl_xor(s, m); qq += __shfl_xor(qq, m); }
  __shared__ float ss[4], sq[4];
  const int wid = tid >> 6;
  if ((tid & 63) == 0) { ss[wid] = s; sq[wid] = qq; }
  __syncthreads();
  s = ss[0] + ss[1] + ss[2] + ss[3];
  qq = sq[0] + sq[1] + sq[2] + sq[3];
  const float mu = s * (1.f / 1024.f);
  const float var = qq * (1.f / 1024.f) - mu * mu;
  const float rstd = rsqrtf(var + 1e-5f);
  f32x4 g = ((const f32x4*)gamma)[tid];
  f32x4 ov;
  ov[0] = (xv[0] - mu) * rstd * g[0];
  ov[1] = (xv[1] - mu) * rstd * g[1];
  ov[2] = (xv[2] - mu) * rstd * g[2];
  ov[3] = (xv[3] - mu) * rstd * g[3];
  ((f32x4*)x)[tid] = ov;
}

extern "C" void kernel_launch(void* const* d_in, const int* in_sizes, int n_in,
                              void* d_out, int out_size, void* d_ws, size_t ws_size,
                              hipStream_t stream) {
  (void)in_sizes; (void)n_in; (void)out_size; (void)ws_size;
  const float* q   = (const float*)d_in[0];
  const float* k   = (const float*)d_in[1];
  const float* v   = (const float*)d_in[2];
  const float* igw = (const float*)d_in[3];
  const float* igb = (const float*)d_in[4];
  const float* fgw = (const float*)d_in[5];
  const float* fgb = (const float*)d_in[6];
  const float* lns = (const float*)d_in[7];
  float* out = (float*)d_out;

  float* gpre = (float*)d_ws;            // [16][4096]
  float* a_g  = gpre + 16 * 4096;        // [16][2048]
  float* ms_g = a_g + 16 * 2048;         // [16][2048]
  float* fl_g = ms_g + 16 * 2048;        // [16][2048]

  gates_kernel<<<dim3(1024), dim3(256), 0, stream>>>(q, k, v, igw, fgw, gpre);
  scan_kernel<<<dim3(16), dim3(256), 0, stream>>>(gpre, igb, fgb, a_g, ms_g, fl_g);
  mlstm_main<<<dim3(512), dim3(512), 0, stream>>>(q, k, v, a_g, ms_g, fl_g, out);
  ln_kernel<<<dim3(4096), dim3(256), 0, stream>>>(out, lns);
}

// Round 8
// 156.721 us; speedup vs baseline: 1.4587x; 1.0567x over previous
//
#include <hip/hip_runtime.h>
#include <hip/hip_bf16.h>

#define SLEN 2048
#define DMODEL 1024
#define NHEAD 8
#define DHEAD 128
#define BM 64
#define BKT 64
#define QSCALE 0.08838834764831845f  // 1/sqrt(128)

typedef __attribute__((ext_vector_type(4))) float f32x4;
typedef __attribute__((ext_vector_type(8))) _Float16 f16x8;
typedef __attribute__((ext_vector_type(4))) _Float16 f16x4;
typedef __attribute__((ext_vector_type(2))) _Float16 f16x2;

static __device__ __forceinline__ int pk16(float a, float b) {
  // pack 2 f32 -> 2 fp16 (RNE) in one u32, a in lo16
  f16x2 t; t[0] = (_Float16)a; t[1] = (_Float16)b;
  union { f16x2 h; int i; } u; u.h = t; return u.i;
}

// ---------------- Kernel 1: gate preactivations (ILP-heavy) -----------------
__global__ __launch_bounds__(256)
void gates_kernel(const float* __restrict__ q, const float* __restrict__ k,
                  const float* __restrict__ v, const float* __restrict__ igw,
                  const float* __restrict__ fgw, float* __restrict__ gpre) {
  const int row0 = blockIdx.x * 4;
  const int tid = threadIdx.x;
  const int lane = tid & 63, wid = tid >> 6;
  const int c4 = tid * 4;
  float acc[64];
  #pragma unroll
  for (int i = 0; i < 64; ++i) acc[i] = 0.f;
  const float* srcs[3] = {q, k, v};
  #pragma unroll
  for (int seg = 0; seg < 3; ++seg) {
    const float* src = srcs[seg];
    f32x4 xv[4];
    #pragma unroll
    for (int r = 0; r < 4; ++r)
      xv[r] = *(const f32x4*)(src + (size_t)(row0 + r) * 1024 + c4);
    #pragma unroll
    for (int g = 0; g < 8; ++g) {
      f32x4 wi = *(const f32x4*)(igw + (size_t)g * 3072 + seg * 1024 + c4);
      f32x4 wf = *(const f32x4*)(fgw + (size_t)g * 3072 + seg * 1024 + c4);
      #pragma unroll
      for (int r = 0; r < 4; ++r) {
        acc[r * 16 + g]     += xv[r][0] * wi[0] + xv[r][1] * wi[1]
                             + xv[r][2] * wi[2] + xv[r][3] * wi[3];
        acc[r * 16 + 8 + g] += xv[r][0] * wf[0] + xv[r][1] * wf[1]
                             + xv[r][2] * wf[2] + xv[r][3] * wf[3];
      }
    }
  }
  __shared__ float red[4][64][4];
  #pragma unroll
  for (int i = 0; i < 64; ++i) {
    float s = acc[i];
    #pragma unroll
    for (int m = 1; m < 16; m <<= 1) s += __shfl_xor(s, m);
    if ((lane & 15) == 0) red[wid][i][lane >> 4] = s;
  }
  __syncthreads();
  if (tid < 64) {
    float s = 0.f;
    #pragma unroll
    for (int w = 0; w < 4; ++w) {
      f32x4 p = *(const f32x4*)&red[w][tid][0];
      s += p[0] + p[1] + p[2] + p[3];
    }
    const int r = tid >> 4, g = tid & 15;
    gpre[(size_t)g * 4096 + row0 + r] = s;
  }
}

// ---------------- Kernel 2: per-(b,h) scans + per-64-tile max ---------------
__global__ __launch_bounds__(256)
void scan_kernel(const float* __restrict__ gpre, const float* __restrict__ igb,
                 const float* __restrict__ fgb, float* __restrict__ a_out,
                 float* __restrict__ ms_out, float* __restrict__ fl_out,
                 float* __restrict__ mt_out) {
  const int bh = blockIdx.x;            // b*8 + h
  const int h = bh & 7;
  const int b = bh >> 3;
  const int tid = threadIdx.x;
  __shared__ double sbd[256];
  __shared__ float sbf[256];
  const int base = b * 2048 + tid * 8;
  const float ig_b = igb[h], fg_b = fgb[h];
  double cs[8];
  float av[8];
  double tot = 0.0;
  #pragma unroll
  for (int e = 0; e < 8; ++e) {
    float x = gpre[(size_t)(8 + h) * 4096 + base + e] + fg_b;
    float l = fminf(x, 0.f) - log1pf(__expf(-fabsf(x)));   // log_sigmoid
    tot += (double)l;
    cs[e] = tot;
  }
  sbd[tid] = tot;
  __syncthreads();
  if (tid == 0) {
    double run = 0.0;
    for (int i = 0; i < 256; ++i) { double t2 = sbd[i]; sbd[i] = run; run += t2; }
  }
  __syncthreads();
  const double excl = sbd[tid];
  float mtot = -3.4e38f;
  #pragma unroll
  for (int e = 0; e < 8; ++e) {
    cs[e] += excl;
    float ig = gpre[(size_t)h * 4096 + base + e] + ig_b;
    av[e] = (float)((double)ig - cs[e]);
    mtot = fmaxf(mtot, av[e]);
  }
  // per-64-window max of a (threads tid..tid+7 cover one window of 64)
  {
    float wmax = mtot;
    wmax = fmaxf(wmax, __shfl_xor(wmax, 1));
    wmax = fmaxf(wmax, __shfl_xor(wmax, 2));
    wmax = fmaxf(wmax, __shfl_xor(wmax, 4));
    if ((tid & 7) == 0) mt_out[bh * 32 + (tid >> 3)] = wmax;
  }
  sbf[tid] = mtot;
  __syncthreads();
  if (tid == 0) {
    float run = -3.4e38f;
    for (int i = 0; i < 256; ++i) { float t2 = sbf[i]; sbf[i] = run; run = fmaxf(run, t2); }
  }
  __syncthreads();
  float run = sbf[tid];
  const int obase = bh * 2048 + tid * 8;
  #pragma unroll
  for (int e = 0; e < 8; ++e) {
    run = fmaxf(run, av[e]);
    a_out[obase + e] = av[e];
    ms_out[obase + e] = run;
    fl_out[obase + e] = __expf(-(float)(cs[e] + (double)run));  // exp(-max_log_D)
  }
}

// ---------------- Kernel 3: main causal mLSTM (swapped QK^T, in-reg C) ------
// grid 512 (heavy t first, pairing). 8 waves = 4 i-groups (wr) x 2 j-halves (wc).
// S^T = mfma(K,Q): lane holds S^T[j][i=l15] -> decay/mask/rowsum lane-local;
// repack to PV A-frags via 8 ds_bpermute + 4 cndmask (no C LDS round-trip).
// Off-diag tiles: decay e_s folded into K staging; 1 expf/lane/iter.
__global__ __launch_bounds__(512)
void mlstm_main(const float* __restrict__ q, const float* __restrict__ k,
                const float* __restrict__ v, const float* __restrict__ a_g,
                const float* __restrict__ ms_g, const float* __restrict__ fl_g,
                const float* __restrict__ mt_g, float* __restrict__ out) {
  __shared__ __align__(16) char pool[50176];
  _Float16* Ks_hi = (_Float16*)pool;                 // [64][128] swz, 16KB
  _Float16* Ks_lo = (_Float16*)(pool + 16384);       // 16KB
  _Float16* Vts   = (_Float16*)(pool + 32768);       // [dv 128][j 64] swz, 16KB
  float* a_s      = (float*)(pool + 49152);          // [64]
  float* rs_lds   = (float*)(pool + 49408);          // [64][2]
  float* hex      = (float*)pool;                    // epilogue reuse (32KB)

  const int bid = blockIdx.x;
  int t, bh;
  if (bid < 256) { t = 31 - (bid >> 4); bh = bid & 15; }      // heavy first
  else           { t = (bid - 256) >> 4; bh = (bid - 256) & 15; }
  const int b = bh >> 3, h = bh & 7;
  const int i0 = t * BM;
  const int tid = threadIdx.x;
  const int lane = tid & 63;
  const int wid = tid >> 6;
  const int wr = wid >> 1;      // i-group 0..3 (16 rows each)
  const int wc = wid & 1;       // j-half 0..1 (32 cols each)
  const int l15 = lane & 15;
  const int lg = lane >> 4;

  const f32x4 z4 = {0.f, 0.f, 0.f, 0.f};

  // ---- Q fragments (QSCALE folded, hi/lo split). Same regs serve as B-op. --
  f16x8 qh[4], ql[4];
  {
    const float* qbase = q + (size_t)(b * SLEN + i0 + wr * 16 + l15) * DMODEL + h * DHEAD;
    #pragma unroll
    for (int ks = 0; ks < 4; ++ks) {
      f32x4 x0 = *(const f32x4*)(qbase + ks * 32 + lg * 8);
      f32x4 x1 = *(const f32x4*)(qbase + ks * 32 + lg * 8 + 4);
      f16x8 hi, lo;
      #pragma unroll
      for (int e = 0; e < 4; ++e) {
        float s0 = x0[e] * QSCALE, s1 = x1[e] * QSCALE;
        _Float16 h0 = (_Float16)s0, h1 = (_Float16)s1;
        hi[e] = h0;     hi[e + 4] = h1;
        lo[e] = (_Float16)(s0 - (float)h0);
        lo[e + 4] = (_Float16)(s1 - (float)h1);
      }
      qh[ks] = hi; ql[ks] = lo;
    }
  }

  // lane's output row for the S^T phase: i = i0 + wr*16 + l15
  const float m_reg = ms_g[bh * SLEN + i0 + wr * 16 + l15];
  const float fl_reg = fl_g[bh * SLEN + i0 + wr * 16 + l15];

  // bpermute index vectors for the repack (byte indices, lane = l15 + 16*lg'):
  // target k-pair p needs source lane lg' = 2*(lg&1) + (p>>1), reg p' = p&1,
  // frag jf' = lg>>1 (selected via cndmask on lane>=32).
  const int lgand1 = lg & 1;
  const int idxA = (l15 + 16 * (2 * lgand1 + 0)) * 4;   // p = 0,1
  const int idxB = (l15 + 16 * (2 * lgand1 + 1)) * 4;   // p = 2,3
  const bool hi_half = (lane >= 32);                    // lg>>1 == 1

  f32x4 hacc[8];
  #pragma unroll
  for (int cf = 0; cf < 8; ++cf) hacc[cf] = z4;
  float ps = 0.f;

  // staging roles
  const int krow = tid >> 3;            // 0..63
  const int kc0 = (tid & 7) * 16;       // K col chunk (16 f32)
  const int vdv = tid & 127;            // V dv
  const int vjq = tid >> 7;             // 0..3, j-quarter (16 j each)

  for (int jt = 0; jt <= t; ++jt) {
    const int j0 = jt * BKT;
    const bool diag = (jt == t);
    const float mt = mt_g[bh * 32 + jt];

    // ---- stage K (fold e_s off-diag), hi/lo split, swizzled ----
    {
      float es = 1.f;
      if (!diag) es = __expf(a_g[bh * SLEN + j0 + krow] - mt);   // <=0 arg
      const float* kp = k + (size_t)(b * SLEN + j0 + krow) * DMODEL + h * DHEAD + kc0;
      char* bh_ = (char*)Ks_hi + krow * 256;
      char* bl_ = (char*)Ks_lo + krow * 256;
      const int sw = (krow & 7) << 4;
      #pragma unroll
      for (int e = 0; e < 4; ++e) {
        f32x4 xv = *(const f32x4*)(kp + e * 4);
        f16x4 hi, lo;
        #pragma unroll
        for (int u = 0; u < 4; ++u) {
          float vv = xv[u] * es;
          _Float16 hh = (_Float16)vv;
          hi[u] = hh; lo[u] = (_Float16)(vv - (float)hh);
        }
        const int bc = (kc0 + e * 4) * 2;
        *(f16x4*)(bh_ + (bc ^ sw)) = hi;
        *(f16x4*)(bl_ + (bc ^ sw)) = lo;
      }
    }
    // ---- stage V: coalesced gathers, vector writes, swizzled [dv][j] ----
    {
      const float* vp = v + (size_t)(b * SLEN + j0 + vjq * 16) * DMODEL + h * DHEAD + vdv;
      float vv[16];
      #pragma unroll
      for (int jj = 0; jj < 16; ++jj)
        vv[jj] = vp[(size_t)jj * DMODEL];
      int pk[8];
      #pragma unroll
      for (int p = 0; p < 8; ++p) pk[p] = pk16(vv[2 * p], vv[2 * p + 1]);
      const int sw = (vdv & 7) << 4;
      char* vb = (char*)Vts + vdv * 128 + vjq * 32;
      *(f32x4*)((char*)Vts + ((vdv * 128 + vjq * 32 + 0) ^ sw)) = *(f32x4*)&pk[0];
      *(f32x4*)((char*)Vts + ((vdv * 128 + vjq * 32 + 16) ^ sw)) = *(f32x4*)&pk[4];
      (void)vb;
    }
    if (diag && tid < BKT) a_s[tid] = a_g[bh * SLEN + j0 + tid];
    __syncthreads();

    // ---- swapped QK^T: sacc[jfl] = S^T[j = wc*32+jfl*16+lg*4+r][i = l15] ----
    f32x4 sacc[2];
    sacc[0] = z4; sacc[1] = z4;
    #pragma unroll
    for (int ks = 0; ks < 4; ++ks) {
      const int bc = ks * 64 + lg * 16;
      #pragma unroll
      for (int jfl = 0; jfl < 2; ++jfl) {
        const int arow = wc * 32 + jfl * 16 + l15;
        const int sw = (arow & 7) << 4;
        f16x8 kh8 = *(const f16x8*)((char*)Ks_hi + arow * 256 + (bc ^ sw));
        f16x8 kl8 = *(const f16x8*)((char*)Ks_lo + arow * 256 + (bc ^ sw));
        sacc[jfl] = __builtin_amdgcn_mfma_f32_16x16x32_f16(kh8, qh[ks], sacc[jfl], 0, 0, 0);
        sacc[jfl] = __builtin_amdgcn_mfma_f32_16x16x32_f16(kl8, qh[ks], sacc[jfl], 0, 0, 0);
        sacc[jfl] = __builtin_amdgcn_mfma_f32_16x16x32_f16(kh8, ql[ks], sacc[jfl], 0, 0, 0);
      }
    }

    // ---- decay + mask + rowsum (lane-local: fixed i = l15-row) ----
    float vals[2][4];
    if (diag) {
      const int iG = i0 + wr * 16 + l15;
      #pragma unroll
      for (int jfl = 0; jfl < 2; ++jfl)
        #pragma unroll
        for (int r = 0; r < 4; ++r) {
          const int jl = wc * 32 + jfl * 16 + lg * 4 + r;
          float e = __expf(fminf(a_s[jl] - m_reg, 0.f));
          float vv = sacc[jfl][r] * e;
          if (j0 + jl > iG) vv = 0.f;
          vals[jfl][r] = vv;
        }
    } else {
      const float em = __expf(fminf(mt - m_reg, 0.f));
      #pragma unroll
      for (int jfl = 0; jfl < 2; ++jfl)
        #pragma unroll
        for (int r = 0; r < 4; ++r)
          vals[jfl][r] = sacc[jfl][r] * em;
    }
    #pragma unroll
    for (int jfl = 0; jfl < 2; ++jfl)
      #pragma unroll
      for (int r = 0; r < 4; ++r) ps += vals[jfl][r];

    // ---- pack + repack to PV A-frag (k = j-within-half, lane row = i) ----
    int c2[2][2];
    #pragma unroll
    for (int jfl = 0; jfl < 2; ++jfl) {
      c2[jfl][0] = pk16(vals[jfl][0], vals[jfl][1]);
      c2[jfl][1] = pk16(vals[jfl][2], vals[jfl][3]);
    }
    int pa32[4];
    #pragma unroll
    for (int p = 0; p < 4; ++p) {
      const int idx = (p < 2) ? idxA : idxB;
      int f0 = __builtin_amdgcn_ds_bpermute(idx, c2[0][p & 1]);
      int f1 = __builtin_amdgcn_ds_bpermute(idx, c2[1][p & 1]);
      pa32[p] = hi_half ? f1 : f0;
    }
    union { int i[4]; f16x8 v; } pu;
    pu.i[0] = pa32[0]; pu.i[1] = pa32[1]; pu.i[2] = pa32[2]; pu.i[3] = pa32[3];
    const f16x8 paf = pu.v;

    // ---- PV: hacc[cf] += PA x V (wave's j-half only) ----
    const int vbc = wc * 64 + lg * 16;
    #pragma unroll
    for (int cf = 0; cf < 8; ++cf) {
      const int vrow = cf * 16 + l15;
      const int sw = (vrow & 7) << 4;
      f16x8 vb8 = *(const f16x8*)((char*)Vts + vrow * 128 + (vbc ^ sw));
      hacc[cf] = __builtin_amdgcn_mfma_f32_16x16x32_f16(paf, vb8, hacc[cf], 0, 0, 0);
    }
    __syncthreads();   // compute done before next stage overwrites
  }

  // ---- epilogue: rowsum across j-partitions, H across j-halves ----
  ps += __shfl_xor(ps, 16);
  ps += __shfl_xor(ps, 32);            // wave-total for row i (= l15-row)
  if (lane < 16) rs_lds[(wr * 16 + l15) * 2 + wc] = ps;
  if (wc == 1) {
    #pragma unroll
    for (int cf = 0; cf < 8; ++cf)
      *(f32x4*)&hex[wr * 2048 + cf * 256 + lane * 4] = hacc[cf];
  }
  __syncthreads();
  if (wc == 0) {
    #pragma unroll
    for (int cf = 0; cf < 8; ++cf) {
      f32x4 o = *(const f32x4*)&hex[wr * 2048 + cf * 256 + lane * 4];
      hacc[cf][0] += o[0]; hacc[cf][1] += o[1];
      hacc[cf][2] += o[2]; hacc[cf][3] += o[3];
    }
    const float rsum = rs_lds[(wr * 16 + l15) * 2 + 0] + rs_lds[(wr * 16 + l15) * 2 + 1];
    const float inv = 1.0f / (fmaxf(fabsf(rsum), fl_reg) + 1e-6f);
    // transpose inv: lane needs inv of rows lg*4+r (held at lanes l15 = lg*4+r)
    union { float f; int i; } uc; uc.f = inv;
    float invr[4];
    #pragma unroll
    for (int r = 0; r < 4; ++r) {
      union { float f; int i; } ur;
      ur.i = __builtin_amdgcn_ds_bpermute((lg * 4 + r) * 4, uc.i);
      invr[r] = ur.f;
    }
    #pragma unroll
    for (int r = 0; r < 4; ++r) {
      const size_t orow = (size_t)(b * SLEN + i0 + wr * 16 + lg * 4 + r) * DMODEL + h * DHEAD;
      #pragma unroll
      for (int cf = 0; cf < 8; ++cf)
        out[orow + cf * 16 + l15] = hacc[cf][r] * invr[r];
    }
  }
}

// ---------------- Kernel 4: in-place LayerNorm on d_out ---------------------
__global__ __launch_bounds__(256)
void ln_kernel(float* __restrict__ out, const float* __restrict__ gamma) {
  const int row = blockIdx.x;
  const int tid = threadIdx.x;
  float* x = out + (size_t)row * DMODEL;
  f32x4 xv = ((const f32x4*)x)[tid];
  float s = xv[0] + xv[1] + xv[2] + xv[3];
  float qq = xv[0] * xv[0] + xv[1] * xv[1] + xv[2] * xv[2] + xv[3] * xv[3];
  #pragma unroll
  for (int m = 1; m < 64; m <<= 1) { s += __shfl_xor(s, m); qq += __shfl_xor(qq, m); }
  __shared__ float ss[4], sq[4];
  const int wid = tid >> 6;
  if ((tid & 63) == 0) { ss[wid] = s; sq[wid] = qq; }
  __syncthreads();
  s = ss[0] + ss[1] + ss[2] + ss[3];
  qq = sq[0] + sq[1] + sq[2] + sq[3];
  const float mu = s * (1.f / 1024.f);
  const float var = qq * (1.f / 1024.f) - mu * mu;
  const float rstd = rsqrtf(var + 1e-5f);
  f32x4 g = ((const f32x4*)gamma)[tid];
  f32x4 ov;
  ov[0] = (xv[0] - mu) * rstd * g[0];
  ov[1] = (xv[1] - mu) * rstd * g[1];
  ov[2] = (xv[2] - mu) * rstd * g[2];
  ov[3] = (xv[3] - mu) * rstd * g[3];
  ((f32x4*)x)[tid] = ov;
}

extern "C" void kernel_launch(void* const* d_in, const int* in_sizes, int n_in,
                              void* d_out, int out_size, void* d_ws, size_t ws_size,
                              hipStream_t stream) {
  (void)in_sizes; (void)n_in; (void)out_size; (void)ws_size;
  const float* q   = (const float*)d_in[0];
  const float* k   = (const float*)d_in[1];
  const float* v   = (const float*)d_in[2];
  const float* igw = (const float*)d_in[3];
  const float* igb = (const float*)d_in[4];
  const float* fgw = (const float*)d_in[5];
  const float* fgb = (const float*)d_in[6];
  const float* lns = (const float*)d_in[7];
  float* out = (float*)d_out;

  float* gpre = (float*)d_ws;            // [16][4096]
  float* a_g  = gpre + 16 * 4096;        // [16][2048]
  float* ms_g = a_g + 16 * 2048;         // [16][2048]
  float* fl_g = ms_g + 16 * 2048;        // [16][2048]
  float* mt_g = fl_g + 16 * 2048;        // [16][32] per-64-tile max of a

  gates_kernel<<<dim3(1024), dim3(256), 0, stream>>>(q, k, v, igw, fgw, gpre);
  scan_kernel<<<dim3(16), dim3(256), 0, stream>>>(gpre, igb, fgb, a_g, ms_g, fl_g, mt_g);
  mlstm_main<<<dim3(512), dim3(512), 0, stream>>>(q, k, v, a_g, ms_g, fl_g, mt_g, out);
  ln_kernel<<<dim3(4096), dim3(256), 0, stream>>>(out, lns);
}

// Round 11
// 110.355 us; speedup vs baseline: 2.0715x; 1.4202x over previous
//
#include <hip/hip_runtime.h>
#include <hip/hip_bf16.h>

#define SLEN 2048
#define DMODEL 1024
#define NHEAD 8
#define DHEAD 128
#define BM 64
#define BKT 64
#define QSCALE 0.08838834764831845f  // 1/sqrt(128)

typedef __attribute__((ext_vector_type(4))) float f32x4;
typedef __attribute__((ext_vector_type(8))) _Float16 f16x8;
typedef __attribute__((ext_vector_type(4))) _Float16 f16x4;
typedef __attribute__((ext_vector_type(2))) _Float16 f16x2;

static __device__ __forceinline__ int pk16(float a, float b) {
  f16x2 t; t[0] = (_Float16)a; t[1] = (_Float16)b;
  union { f16x2 h; int i; } u; u.h = t; return u.i;
}
static __device__ __forceinline__ unsigned short f16bits(float x) {
  union { _Float16 h; unsigned short u; } u2; u2.h = (_Float16)x; return u2.u;
}

// ---------------- Kernel 1: gate preactivations (verified) ------------------
__global__ __launch_bounds__(256)
void gates_kernel(const float* __restrict__ q, const float* __restrict__ k,
                  const float* __restrict__ v, const float* __restrict__ igw,
                  const float* __restrict__ fgw, float* __restrict__ gpre) {
  const int row0 = blockIdx.x * 4;
  const int tid = threadIdx.x;
  const int lane = tid & 63, wid = tid >> 6;
  const int c4 = tid * 4;
  float acc[64];
  #pragma unroll
  for (int i = 0; i < 64; ++i) acc[i] = 0.f;
  const float* srcs[3] = {q, k, v};
  #pragma unroll
  for (int seg = 0; seg < 3; ++seg) {
    const float* src = srcs[seg];
    f32x4 xv[4];
    #pragma unroll
    for (int r = 0; r < 4; ++r)
      xv[r] = *(const f32x4*)(src + (size_t)(row0 + r) * 1024 + c4);
    #pragma unroll
    for (int g = 0; g < 8; ++g) {
      f32x4 wi = *(const f32x4*)(igw + (size_t)g * 3072 + seg * 1024 + c4);
      f32x4 wf = *(const f32x4*)(fgw + (size_t)g * 3072 + seg * 1024 + c4);
      #pragma unroll
      for (int r = 0; r < 4; ++r) {
        acc[r * 16 + g]     += xv[r][0] * wi[0] + xv[r][1] * wi[1]
                             + xv[r][2] * wi[2] + xv[r][3] * wi[3];
        acc[r * 16 + 8 + g] += xv[r][0] * wf[0] + xv[r][1] * wf[1]
                             + xv[r][2] * wf[2] + xv[r][3] * wf[3];
      }
    }
  }
  __shared__ float red[4][64][4];
  #pragma unroll
  for (int i = 0; i < 64; ++i) {
    float s = acc[i];
    #pragma unroll
    for (int m = 1; m < 16; m <<= 1) s += __shfl_xor(s, m);
    if ((lane & 15) == 0) red[wid][i][lane >> 4] = s;
  }
  __syncthreads();
  if (tid < 64) {
    float s = 0.f;
    #pragma unroll
    for (int w = 0; w < 4; ++w) {
      f32x4 p = *(const f32x4*)&red[w][tid][0];
      s += p[0] + p[1] + p[2] + p[3];
    }
    const int r = tid >> 4, g = tid & 15;
    gpre[(size_t)g * 4096 + row0 + r] = s;
  }
}

// ---------------- Kernel 2: scans + chunk maxima (64 and 128) ---------------
__global__ __launch_bounds__(256)
void scan_kernel(const float* __restrict__ gpre, const float* __restrict__ igb,
                 const float* __restrict__ fgb, float* __restrict__ a_out,
                 float* __restrict__ ms_out, float* __restrict__ fl_out,
                 float* __restrict__ mt64, float* __restrict__ mt128,
                 float* __restrict__ Mg_out) {
  const int bh = blockIdx.x;
  const int h = bh & 7;
  const int b = bh >> 3;
  const int tid = threadIdx.x;
  __shared__ double sbd[256];
  __shared__ float sbf[256];
  __shared__ float mt_l[16];
  const int base = b * 2048 + tid * 8;
  const float ig_b = igb[h], fg_b = fgb[h];
  double cs[8];
  float av[8];
  double tot = 0.0;
  #pragma unroll
  for (int e = 0; e < 8; ++e) {
    float x = gpre[(size_t)(8 + h) * 4096 + base + e] + fg_b;
    float l = fminf(x, 0.f) - log1pf(__expf(-fabsf(x)));   // log_sigmoid
    tot += (double)l;
    cs[e] = tot;
  }
  sbd[tid] = tot;
  __syncthreads();
  if (tid == 0) {
    double run = 0.0;
    for (int i = 0; i < 256; ++i) { double t2 = sbd[i]; sbd[i] = run; run += t2; }
  }
  __syncthreads();
  const double excl = sbd[tid];
  float mtot = -3.4e38f;
  #pragma unroll
  for (int e = 0; e < 8; ++e) {
    cs[e] += excl;
    float ig = gpre[(size_t)h * 4096 + base + e] + ig_b;
    av[e] = (float)((double)ig - cs[e]);
    mtot = fmaxf(mtot, av[e]);
  }
  // per-64 and per-128 window maxima
  {
    float w8 = mtot;
    w8 = fmaxf(w8, __shfl_xor(w8, 1));
    w8 = fmaxf(w8, __shfl_xor(w8, 2));
    w8 = fmaxf(w8, __shfl_xor(w8, 4));
    if ((tid & 7) == 0) mt64[bh * 32 + (tid >> 3)] = w8;
    float w16 = fmaxf(w8, __shfl_xor(w8, 8));
    if ((tid & 15) == 0) { mt128[bh * 16 + (tid >> 4)] = w16; mt_l[tid >> 4] = w16; }
  }
  sbf[tid] = mtot;
  __syncthreads();
  if (tid == 0) {
    float run = -3.4e38f;
    for (int i = 0; i < 256; ++i) { float t2 = sbf[i]; sbf[i] = run; run = fmaxf(run, t2); }
    float M = -3.4e38f;
    for (int c = 0; c < 16; ++c) { Mg_out[bh * 16 + c] = M; M = fmaxf(M, mt_l[c]); }
  }
  __syncthreads();
  float run = sbf[tid];
  const int obase = bh * 2048 + tid * 8;
  #pragma unroll
  for (int e = 0; e < 8; ++e) {
    run = fmaxf(run, av[e]);
    a_out[obase + e] = av[e];
    ms_out[obase + e] = run;
    fl_out[obase + e] = __expf(-(float)(cs[e] + (double)run));  // exp(-max_log_D)
  }
}

// ---------------- Kernel P1: per-128-chunk state G[dv][dk] (fp16) + ksum ----
// G_c = sum_{j in chunk} exp(a_j - mt128_c) V[j][dv] K[j][dk]; two 64-j passes.
__global__ __launch_bounds__(512)
void p1_kernel(const float* __restrict__ k, const float* __restrict__ v,
               const float* __restrict__ a_g, const float* __restrict__ mt128,
               unsigned short* __restrict__ GXs, float* __restrict__ pkt) {
  __shared__ __align__(16) char pool[33280];
  _Float16* Kts = (_Float16*)pool;             // [128 dk][64 j] 128B rows, swz
  _Float16* Vts = (_Float16*)(pool + 16384);   // [128 dv][64 j]
  float* w_s = (float*)(pool + 32768);         // [128]
  const int c = blockIdx.x, bh = blockIdx.y;
  const int b = bh >> 3, h = bh & 7;
  const int tid = threadIdx.x;
  const int lane = tid & 63, wid = tid >> 6;
  const int l15 = lane & 15, lg = lane >> 4;
  if (tid < 128) w_s[tid] = __expf(a_g[bh * SLEN + c * 128 + tid] - mt128[bh * 16 + c]);
  const f32x4 z4 = {0.f, 0.f, 0.f, 0.f};
  f32x4 acc[8];
  #pragma unroll
  for (int i = 0; i < 8; ++i) acc[i] = z4;
  float ks_acc = 0.f;
  for (int p = 0; p < 2; ++p) {
    const int j0 = c * 128 + p * 64;
    __syncthreads();   // w_s ready (p=0); prior pass reads done (p=1)
    {
      const int d = tid & 127;
      const int jq = tid >> 7;                 // 0..3 (16 j each)
      const size_t rowb = (size_t)(b * SLEN + j0 + jq * 16) * DMODEL + h * DHEAD + d;
      float kv[16], vv[16];
      #pragma unroll
      for (int jj = 0; jj < 16; ++jj) {
        kv[jj] = k[rowb + (size_t)jj * DMODEL] * w_s[p * 64 + jq * 16 + jj];
        vv[jj] = v[rowb + (size_t)jj * DMODEL];
      }
      int ph[8], pv[8];
      #pragma unroll
      for (int pp = 0; pp < 8; ++pp) {
        ph[pp] = pk16(kv[2 * pp], kv[2 * pp + 1]);
        pv[pp] = pk16(vv[2 * pp], vv[2 * pp + 1]);
      }
      const int sw = (d & 7) << 4;
      const int b0 = d * 128 + jq * 32;
      *(f32x4*)((char*)Kts + ((b0 + 0) ^ sw))  = *(f32x4*)&ph[0];
      *(f32x4*)((char*)Kts + ((b0 + 16) ^ sw)) = *(f32x4*)&ph[4];
      *(f32x4*)((char*)Vts + ((b0 + 0) ^ sw))  = *(f32x4*)&pv[0];
      *(f32x4*)((char*)Vts + ((b0 + 16) ^ sw)) = *(f32x4*)&pv[4];
    }
    __syncthreads();
    f16x8 avv[2];
    {
      const int row = wid * 16 + l15;
      const int sw = (l15 & 7) << 4;
      avv[0] = *(const f16x8*)((char*)Vts + row * 128 + ((lg * 16) ^ sw));
      avv[1] = *(const f16x8*)((char*)Vts + row * 128 + ((64 + lg * 16) ^ sw));
    }
    #pragma unroll
    for (int dkt = 0; dkt < 8; ++dkt) {
      const int row = dkt * 16 + l15;
      const int sw = (l15 & 7) << 4;
      #pragma unroll
      for (int ks = 0; ks < 2; ++ks) {
        const int bc = ks * 64 + lg * 16;
        f16x8 bh8 = *(const f16x8*)((char*)Kts + row * 128 + (bc ^ sw));
        acc[dkt] = __builtin_amdgcn_mfma_f32_16x16x32_f16(avv[ks], bh8, acc[dkt], 0, 0, 0);
      }
    }
    if (tid < 128) {   // ksum partial over this pass's 64 j
      const int sw = (tid & 7) << 4;
      #pragma unroll
      for (int g = 0; g < 8; ++g) {
        f16x8 hh = *(const f16x8*)((char*)Kts + tid * 128 + ((g * 16) ^ sw));
        #pragma unroll
        for (int e = 0; e < 8; ++e) ks_acc += (float)hh[e];
      }
    }
  }
  unsigned short* gxs = GXs + (size_t)(bh * 16 + c) * 16384;
  #pragma unroll
  for (int dkt = 0; dkt < 8; ++dkt)
    #pragma unroll
    for (int r = 0; r < 4; ++r)
      gxs[(wid * 16 + lg * 4 + r) * 128 + dkt * 16 + l15] = f16bits(acc[dkt][r]);
  if (tid < 128) pkt[(size_t)(bh * 16 + c) * 128 + tid] = ks_acc;
}

// ---------------- Kernel P2: exclusive prefix states (in-place, fp16) -------
// X_c = sum_{c'<c} exp(mt_c' - Mg_c) G_c'; snapshot written before adding G_c.
__global__ __launch_bounds__(256)
void p2_kernel(const float* __restrict__ mt128, unsigned short* __restrict__ GXs,
               const float* __restrict__ pkt, float* __restrict__ pkx) {
  const int s = blockIdx.x, bh = blockIdx.y;
  const int tid = threadIdx.x;
  union U8 { uint4 q; _Float16 h[8]; };
  if (s < 8) {
    unsigned short* base = GXs + (size_t)bh * 16 * 16384 + s * 2048 + tid * 8;
    float X[8];
    #pragma unroll
    for (int e = 0; e < 8; ++e) X[e] = 0.f;
    float Mm1 = -3.4e38f;
    for (int c = 0; c < 16; ++c) {
      U8 cu; cu.q = *(const uint4*)(base + (size_t)c * 16384);
      const float mtc = mt128[bh * 16 + c];
      const float Mc = fmaxf(Mm1, mtc);
      const float s1 = __expf(Mm1 - Mc), s2 = __expf(mtc - Mc);
      U8 ou;
      #pragma unroll
      for (int e = 0; e < 8; ++e) ou.h[e] = (_Float16)X[e];
      *(uint4*)(base + (size_t)c * 16384) = ou.q;
      #pragma unroll
      for (int e = 0; e < 8; ++e) X[e] = X[e] * s1 + (float)cu.h[e] * s2;
      Mm1 = Mc;
    }
  } else if (tid < 128) {
    const float* pb = pkt + (size_t)bh * 16 * 128 + tid;
    float X = 0.f, Mm1 = -3.4e38f;
    for (int c = 0; c < 16; ++c) {
      const float g = pb[(size_t)c * 128];
      const float mtc = mt128[bh * 16 + c];
      const float Mc = fmaxf(Mm1, mtc);
      pkx[(size_t)bh * 16 * 128 + (size_t)c * 128 + tid] = X;
      X = X * __expf(Mm1 - Mc) + g * __expf(mtc - Mc);
      Mm1 = Mc;
    }
  }
}

// ---------------- Kernel P3: intra sub-tiles + state multiply ---------------
// grid 512 = (t 0..31, bh). chunk c = t>>1. Phase B: hacc += (e_i*Q) @ X_c.
// Phase A: 1 (t even) or 2 (t odd) 64-wide sub-tiles, verified R8 diag path.
__global__ __launch_bounds__(512)
void p3_kernel(const float* __restrict__ q, const float* __restrict__ k,
               const float* __restrict__ v, const float* __restrict__ a_g,
               const float* __restrict__ ms_g, const float* __restrict__ fl_g,
               const float* __restrict__ Mg_g, const float* __restrict__ pkx,
               const unsigned short* __restrict__ GXs, float* __restrict__ out) {
  __shared__ __align__(16) char pool[50432];
  // phase B: Xs fp16 [128][128] @0 (32KB), pks @49920
  // phase A: Ks_hi @0, Ks_lo @16384, Vts @32768, a_s @49152
  // epilogue: hex @0 (32KB), rs_lds @49408
  _Float16* Ks_hi = (_Float16*)pool;
  _Float16* Ks_lo = (_Float16*)(pool + 16384);
  _Float16* Vts   = (_Float16*)(pool + 32768);
  float* a_s      = (float*)(pool + 49152);
  float* rs_lds   = (float*)(pool + 49408);
  float* pks      = (float*)(pool + 49920);
  float* hex      = (float*)pool;

  const int bid = blockIdx.x;
  const int t = bid >> 4;
  const int bh = bid & 15;
  const int b = bh >> 3, h = bh & 7;
  const int c = t >> 1;
  const int i0 = t * BM;
  const int tid = threadIdx.x;
  const int lane = tid & 63;
  const int wid = tid >> 6;
  const int wr = wid >> 1;
  const int wc = wid & 1;
  const int l15 = lane & 15;
  const int lg = lane >> 4;
  const f32x4 z4 = {0.f, 0.f, 0.f, 0.f};

  // ---- Q fragments (QSCALE folded, hi/lo split) ----
  f16x8 qh[4], ql[4];
  {
    const float* qbase = q + (size_t)(b * SLEN + i0 + wr * 16 + l15) * DMODEL + h * DHEAD;
    #pragma unroll
    for (int ks = 0; ks < 4; ++ks) {
      f32x4 x0 = *(const f32x4*)(qbase + ks * 32 + lg * 8);
      f32x4 x1 = *(const f32x4*)(qbase + ks * 32 + lg * 8 + 4);
      f16x8 hi, lo;
      #pragma unroll
      for (int e = 0; e < 4; ++e) {
        float s0 = x0[e] * QSCALE, s1 = x1[e] * QSCALE;
        _Float16 h0 = (_Float16)s0, h1 = (_Float16)s1;
        hi[e] = h0;     hi[e + 4] = h1;
        lo[e] = (_Float16)(s0 - (float)h0);
        lo[e + 4] = (_Float16)(s1 - (float)h1);
      }
      qh[ks] = hi; ql[ks] = lo;
    }
  }
  const float m_reg = ms_g[bh * SLEN + i0 + wr * 16 + l15];
  const float fl_reg = fl_g[bh * SLEN + i0 + wr * 16 + l15];
  const float e_l = __expf(Mg_g[bh * 16 + c] - m_reg);   // 0 at c==0

  f32x4 hacc[8];
  #pragma unroll
  for (int cf = 0; cf < 8; ++cf) hacc[cf] = z4;
  float ps = 0.f;

  // ================= Phase B: inter-chunk state multiply ===================
  {
    const unsigned short* gxs = GXs + (size_t)(bh * 16 + c) * 16384;
    const int row = tid >> 2;
    const int c0b = (tid & 3) * 64;
    const int sw = (row & 7) << 4;
    #pragma unroll
    for (int e = 0; e < 4; ++e) {
      uint4 g4 = *(const uint4*)((const char*)gxs + row * 256 + c0b + e * 16);
      *(uint4*)((char*)pool + row * 256 + ((c0b + e * 16) ^ sw)) = g4;
    }
    if (tid < 128) pks[tid] = pkx[(size_t)(bh * 16 + c) * 128 + tid];
  }
  __syncthreads();
  {
    f16x8 qeh[2], qel[2];
    #pragma unroll
    for (int kss = 0; kss < 2; ++kss) {
      const int ks = wc * 2 + kss;
      #pragma unroll
      for (int e = 0; e < 8; ++e) {
        float qf = ((float)qh[ks][e] + (float)ql[ks][e]) * e_l;
        _Float16 hh = (_Float16)qf;
        qeh[kss][e] = hh; qel[kss][e] = (_Float16)(qf - (float)hh);
      }
    }
    #pragma unroll
    for (int cf = 0; cf < 8; ++cf) {
      const int row = cf * 16 + l15;
      const int sw = (l15 & 7) << 4;
      #pragma unroll
      for (int kss = 0; kss < 2; ++kss) {
        const int bc = (wc * 2 + kss) * 64 + lg * 16;
        f16x8 xh = *(const f16x8*)((char*)pool + row * 256 + (bc ^ sw));
        hacc[cf] = __builtin_amdgcn_mfma_f32_16x16x32_f16(qeh[kss], xh, hacc[cf], 0, 0, 0);
        hacc[cf] = __builtin_amdgcn_mfma_f32_16x16x32_f16(qel[kss], xh, hacc[cf], 0, 0, 0);
      }
    }
  }
  if (wc == 0) {   // inter rowsum partial: e_l * (q . pk_excl)
    float dot = 0.f;
    #pragma unroll
    for (int ks = 0; ks < 4; ++ks)
      #pragma unroll
      for (int e = 0; e < 8; ++e)
        dot += ((float)qh[ks][e] + (float)ql[ks][e]) * pks[ks * 32 + lg * 8 + e];
    ps += dot * e_l;
  }

  // ================= Phase A: intra sub-tiles (verified R8 path) ===========
  const int npass = 1 + (t & 1);
  for (int pss = 0; pss < npass; ++pss) {
    const int j0 = c * 128 + pss * 64;
    __syncthreads();   // phase B / prior pass reads done before restage
    {
      const int krow = tid >> 3;
      const int kc0 = (tid & 7) * 16;
      const float* kp = k + (size_t)(b * SLEN + j0 + krow) * DMODEL + h * DHEAD + kc0;
      char* bh_ = (char*)Ks_hi + krow * 256;
      char* bl_ = (char*)Ks_lo + krow * 256;
      const int sw = (krow & 7) << 4;
      #pragma unroll
      for (int e = 0; e < 4; ++e) {
        f32x4 xv = *(const f32x4*)(kp + e * 4);
        f16x4 hi, lo;
        #pragma unroll
        for (int u = 0; u < 4; ++u) {
          _Float16 hh = (_Float16)xv[u];
          hi[u] = hh; lo[u] = (_Float16)(xv[u] - (float)hh);
        }
        const int bc = (kc0 + e * 4) * 2;
        *(f16x4*)(bh_ + (bc ^ sw)) = hi;
        *(f16x4*)(bl_ + (bc ^ sw)) = lo;
      }
    }
    {
      const int j = tid & 63;
      const int grp = tid >> 6;
      const float* vp = v + (size_t)(b * SLEN + j0 + j) * DMODEL + h * DHEAD;
      #pragma unroll
      for (int cc = 0; cc < 4; ++cc) {
        const int dv0 = grp * 16 + cc * 4;
        f32x4 xv = *(const f32x4*)(vp + dv0);
        #pragma unroll
        for (int e = 0; e < 4; ++e) {
          const int dv = dv0 + e;
          *(_Float16*)((char*)Vts + dv * 128 + ((j * 2) ^ ((dv & 7) << 4))) = (_Float16)xv[e];
        }
      }
    }
    if (tid < BKT) a_s[tid] = a_g[bh * SLEN + j0 + tid];
    __syncthreads();

    // swapped QK^T
    f32x4 sacc[2];
    sacc[0] = z4; sacc[1] = z4;
    #pragma unroll
    for (int ks = 0; ks < 4; ++ks) {
      const int bc = ks * 64 + lg * 16;
      #pragma unroll
      for (int jfl = 0; jfl < 2; ++jfl) {
        const int arow = wc * 32 + jfl * 16 + l15;
        const int sw = (arow & 7) << 4;
        f16x8 kh8 = *(const f16x8*)((char*)Ks_hi + arow * 256 + (bc ^ sw));
        f16x8 kl8 = *(const f16x8*)((char*)Ks_lo + arow * 256 + (bc ^ sw));
        sacc[jfl] = __builtin_amdgcn_mfma_f32_16x16x32_f16(kh8, qh[ks], sacc[jfl], 0, 0, 0);
        sacc[jfl] = __builtin_amdgcn_mfma_f32_16x16x32_f16(kl8, qh[ks], sacc[jfl], 0, 0, 0);
        sacc[jfl] = __builtin_amdgcn_mfma_f32_16x16x32_f16(kh8, ql[ks], sacc[jfl], 0, 0, 0);
      }
    }
    // decay + mask + rowsum (lane-local, i = l15-row); mask idle on full tiles
    float vals[2][4];
    {
      const int iG = i0 + wr * 16 + l15;
      #pragma unroll
      for (int jfl = 0; jfl < 2; ++jfl)
        #pragma unroll
        for (int r = 0; r < 4; ++r) {
          const int jl = wc * 32 + jfl * 16 + lg * 4 + r;
          float e = __expf(fminf(a_s[jl] - m_reg, 0.f));
          float vv = sacc[jfl][r] * e;
          if (j0 + jl > iG) vv = 0.f;
          ps += vv;
          vals[jfl][r] = vv;
        }
    }
    // pack + repack to PV A-frag via bpermute
    const int lgand1 = lg & 1;
    const int idxA = (l15 + 16 * (2 * lgand1 + 0)) * 4;
    const int idxB = (l15 + 16 * (2 * lgand1 + 1)) * 4;
    const bool hi_half = (lane >= 32);
    int c2[2][2];
    #pragma unroll
    for (int jfl = 0; jfl < 2; ++jfl) {
      c2[jfl][0] = pk16(vals[jfl][0], vals[jfl][1]);
      c2[jfl][1] = pk16(vals[jfl][2], vals[jfl][3]);
    }
    int pa32[4];
    #pragma unroll
    for (int p = 0; p < 4; ++p) {
      const int idx = (p < 2) ? idxA : idxB;
      int f0 = __builtin_amdgcn_ds_bpermute(idx, c2[0][p & 1]);
      int f1 = __builtin_amdgcn_ds_bpermute(idx, c2[1][p & 1]);
      pa32[p] = hi_half ? f1 : f0;
    }
    union { int i[4]; f16x8 v; } pu;
    pu.i[0] = pa32[0]; pu.i[1] = pa32[1]; pu.i[2] = pa32[2]; pu.i[3] = pa32[3];
    const f16x8 paf = pu.v;

    // PV
    const int vbc = wc * 64 + lg * 16;
    #pragma unroll
    for (int cf = 0; cf < 8; ++cf) {
      const int vrow = cf * 16 + l15;
      const int sw = (vrow & 7) << 4;
      f16x8 vb8 = *(const f16x8*)((char*)Vts + vrow * 128 + (vbc ^ sw));
      hacc[cf] = __builtin_amdgcn_mfma_f32_16x16x32_f16(paf, vb8, hacc[cf], 0, 0, 0);
    }
  }
  __syncthreads();

  // ================= Epilogue (verified R8) ================================
  ps += __shfl_xor(ps, 16);
  ps += __shfl_xor(ps, 32);
  if (lane < 16) rs_lds[(wr * 16 + l15) * 2 + wc] = ps;
  if (wc == 1) {
    #pragma unroll
    for (int cf = 0; cf < 8; ++cf)
      *(f32x4*)&hex[wr * 2048 + cf * 256 + lane * 4] = hacc[cf];
  }
  __syncthreads();
  if (wc == 0) {
    #pragma unroll
    for (int cf = 0; cf < 8; ++cf) {
      f32x4 o = *(const f32x4*)&hex[wr * 2048 + cf * 256 + lane * 4];
      hacc[cf][0] += o[0]; hacc[cf][1] += o[1];
      hacc[cf][2] += o[2]; hacc[cf][3] += o[3];
    }
    const float rsum = rs_lds[(wr * 16 + l15) * 2 + 0] + rs_lds[(wr * 16 + l15) * 2 + 1];
    const float inv = 1.0f / (fmaxf(fabsf(rsum), fl_reg) + 1e-6f);
    union { float f; int i; } uc; uc.f = inv;
    float invr[4];
    #pragma unroll
    for (int r = 0; r < 4; ++r) {
      union { float f; int i; } ur;
      ur.i = __builtin_amdgcn_ds_bpermute((lg * 4 + r) * 4, uc.i);
      invr[r] = ur.f;
    }
    #pragma unroll
    for (int r = 0; r < 4; ++r) {
      const size_t orow = (size_t)(b * SLEN + i0 + wr * 16 + lg * 4 + r) * DMODEL + h * DHEAD;
      #pragma unroll
      for (int cf = 0; cf < 8; ++cf)
        out[orow + cf * 16 + l15] = hacc[cf][r] * invr[r];
    }
  }
}

// ---------------- Fallback: R8 mlstm_main (verified, ws-light) --------------
__global__ __launch_bounds__(512)
void mlstm_main(const float* __restrict__ q, const float* __restrict__ k,
                const float* __restrict__ v, const float* __restrict__ a_g,
                const float* __restrict__ ms_g, const float* __restrict__ fl_g,
                const float* __restrict__ mt_g, float* __restrict__ out) {
  __shared__ __align__(16) char pool[50176];
  _Float16* Ks_hi = (_Float16*)pool;
  _Float16* Ks_lo = (_Float16*)(pool + 16384);
  _Float16* Vts   = (_Float16*)(pool + 32768);
  float* a_s      = (float*)(pool + 49152);
  float* rs_lds   = (float*)(pool + 49408);
  float* hex      = (float*)pool;

  const int bid = blockIdx.x;
  int t, bh;
  if (bid < 256) { t = 31 - (bid >> 4); bh = bid & 15; }
  else           { t = (bid - 256) >> 4; bh = (bid - 256) & 15; }
  const int b = bh >> 3, h = bh & 7;
  const int i0 = t * BM;
  const int tid = threadIdx.x;
  const int lane = tid & 63;
  const int wid = tid >> 6;
  const int wr = wid >> 1;
  const int wc = wid & 1;
  const int l15 = lane & 15;
  const int lg = lane >> 4;
  const f32x4 z4 = {0.f, 0.f, 0.f, 0.f};

  f16x8 qh[4], ql[4];
  {
    const float* qbase = q + (size_t)(b * SLEN + i0 + wr * 16 + l15) * DMODEL + h * DHEAD;
    #pragma unroll
    for (int ks = 0; ks < 4; ++ks) {
      f32x4 x0 = *(const f32x4*)(qbase + ks * 32 + lg * 8);
      f32x4 x1 = *(const f32x4*)(qbase + ks * 32 + lg * 8 + 4);
      f16x8 hi, lo;
      #pragma unroll
      for (int e = 0; e < 4; ++e) {
        float s0 = x0[e] * QSCALE, s1 = x1[e] * QSCALE;
        _Float16 h0 = (_Float16)s0, h1 = (_Float16)s1;
        hi[e] = h0;     hi[e + 4] = h1;
        lo[e] = (_Float16)(s0 - (float)h0);
        lo[e + 4] = (_Float16)(s1 - (float)h1);
      }
      qh[ks] = hi; ql[ks] = lo;
    }
  }
  const float m_reg = ms_g[bh * SLEN + i0 + wr * 16 + l15];
  const float fl_reg = fl_g[bh * SLEN + i0 + wr * 16 + l15];
  const int lgand1 = lg & 1;
  const int idxA = (l15 + 16 * (2 * lgand1 + 0)) * 4;
  const int idxB = (l15 + 16 * (2 * lgand1 + 1)) * 4;
  const bool hi_half = (lane >= 32);

  f32x4 hacc[8];
  #pragma unroll
  for (int cf = 0; cf < 8; ++cf) hacc[cf] = z4;
  float ps = 0.f;

  const int krow = tid >> 3;
  const int kc0 = (tid & 7) * 16;
  const int vdv = tid & 127;
  const int vjq = tid >> 7;

  for (int jt = 0; jt <= t; ++jt) {
    const int j0 = jt * BKT;
    const bool diag = (jt == t);
    const float mt = mt_g[bh * 32 + jt];
    {
      float es = 1.f;
      if (!diag) es = __expf(a_g[bh * SLEN + j0 + krow] - mt);
      const float* kp = k + (size_t)(b * SLEN + j0 + krow) * DMODEL + h * DHEAD + kc0;
      char* bh_ = (char*)Ks_hi + krow * 256;
      char* bl_ = (char*)Ks_lo + krow * 256;
      const int sw = (krow & 7) << 4;
      #pragma unroll
      for (int e = 0; e < 4; ++e) {
        f32x4 xv = *(const f32x4*)(kp + e * 4);
        f16x4 hi, lo;
        #pragma unroll
        for (int u = 0; u < 4; ++u) {
          float vv = xv[u] * es;
          _Float16 hh = (_Float16)vv;
          hi[u] = hh; lo[u] = (_Float16)(vv - (float)hh);
        }
        const int bc = (kc0 + e * 4) * 2;
        *(f16x4*)(bh_ + (bc ^ sw)) = hi;
        *(f16x4*)(bl_ + (bc ^ sw)) = lo;
      }
    }
    {
      const float* vp = v + (size_t)(b * SLEN + j0 + vjq * 16) * DMODEL + h * DHEAD + vdv;
      float vv[16];
      #pragma unroll
      for (int jj = 0; jj < 16; ++jj)
        vv[jj] = vp[(size_t)jj * DMODEL];
      int pk[8];
      #pragma unroll
      for (int p = 0; p < 8; ++p) pk[p] = pk16(vv[2 * p], vv[2 * p + 1]);
      const int sw = (vdv & 7) << 4;
      *(f32x4*)((char*)Vts + ((vdv * 128 + vjq * 32 + 0) ^ sw)) = *(f32x4*)&pk[0];
      *(f32x4*)((char*)Vts + ((vdv * 128 + vjq * 32 + 16) ^ sw)) = *(f32x4*)&pk[4];
    }
    if (diag && tid < BKT) a_s[tid] = a_g[bh * SLEN + j0 + tid];
    __syncthreads();

    f32x4 sacc[2];
    sacc[0] = z4; sacc[1] = z4;
    #pragma unroll
    for (int ks = 0; ks < 4; ++ks) {
      const int bc = ks * 64 + lg * 16;
      #pragma unroll
      for (int jfl = 0; jfl < 2; ++jfl) {
        const int arow = wc * 32 + jfl * 16 + l15;
        const int sw = (arow & 7) << 4;
        f16x8 kh8 = *(const f16x8*)((char*)Ks_hi + arow * 256 + (bc ^ sw));
        f16x8 kl8 = *(const f16x8*)((char*)Ks_lo + arow * 256 + (bc ^ sw));
        sacc[jfl] = __builtin_amdgcn_mfma_f32_16x16x32_f16(kh8, qh[ks], sacc[jfl], 0, 0, 0);
        sacc[jfl] = __builtin_amdgcn_mfma_f32_16x16x32_f16(kl8, qh[ks], sacc[jfl], 0, 0, 0);
        sacc[jfl] = __builtin_amdgcn_mfma_f32_16x16x32_f16(kh8, ql[ks], sacc[jfl], 0, 0, 0);
      }
    }
    float vals[2][4];
    if (diag) {
      const int iG = i0 + wr * 16 + l15;
      #pragma unroll
      for (int jfl = 0; jfl < 2; ++jfl)
        #pragma unroll
        for (int r = 0; r < 4; ++r) {
          const int jl = wc * 32 + jfl * 16 + lg * 4 + r;
          float e = __expf(fminf(a_s[jl] - m_reg, 0.f));
          float vv = sacc[jfl][r] * e;
          if (j0 + jl > iG) vv = 0.f;
          vals[jfl][r] = vv;
        }
    } else {
      const float em = __expf(fminf(mt - m_reg, 0.f));
      #pragma unroll
      for (int jfl = 0; jfl < 2; ++jfl)
        #pragma unroll
        for (int r = 0; r < 4; ++r)
          vals[jfl][r] = sacc[jfl][r] * em;
    }
    #pragma unroll
    for (int jfl = 0; jfl < 2; ++jfl)
      #pragma unroll
      for (int r = 0; r < 4; ++r) ps += vals[jfl][r];

    int c2[2][2];
    #pragma unroll
    for (int jfl = 0; jfl < 2; ++jfl) {
      c2[jfl][0] = pk16(vals[jfl][0], vals[jfl][1]);
      c2[jfl][1] = pk16(vals[jfl][2], vals[jfl][3]);
    }
    int pa32[4];
    #pragma unroll
    for (int p = 0; p < 4; ++p) {
      const int idx = (p < 2) ? idxA : idxB;
      int f0 = __builtin_amdgcn_ds_bpermute(idx, c2[0][p & 1]);
      int f1 = __builtin_amdgcn_ds_bpermute(idx, c2[1][p & 1]);
      pa32[p] = hi_half ? f1 : f0;
    }
    union { int i[4]; f16x8 v; } pu;
    pu.i[0] = pa32[0]; pu.i[1] = pa32[1]; pu.i[2] = pa32[2]; pu.i[3] = pa32[3];
    const f16x8 paf = pu.v;

    const int vbc = wc * 64 + lg * 16;
    #pragma unroll
    for (int cf = 0; cf < 8; ++cf) {
      const int vrow = cf * 16 + l15;
      const int sw = (vrow & 7) << 4;
      f16x8 vb8 = *(const f16x8*)((char*)Vts + vrow * 128 + (vbc ^ sw));
      hacc[cf] = __builtin_amdgcn_mfma_f32_16x16x32_f16(paf, vb8, hacc[cf], 0, 0, 0);
    }
    __syncthreads();
  }

  ps += __shfl_xor(ps, 16);
  ps += __shfl_xor(ps, 32);
  if (lane < 16) rs_lds[(wr * 16 + l15) * 2 + wc] = ps;
  if (wc == 1) {
    #pragma unroll
    for (int cf = 0; cf < 8; ++cf)
      *(f32x4*)&hex[wr * 2048 + cf * 256 + lane * 4] = hacc[cf];
  }
  __syncthreads();
  if (wc == 0) {
    #pragma unroll
    for (int cf = 0; cf < 8; ++cf) {
      f32x4 o = *(const f32x4*)&hex[wr * 2048 + cf * 256 + lane * 4];
      hacc[cf][0] += o[0]; hacc[cf][1] += o[1];
      hacc[cf][2] += o[2]; hacc[cf][3] += o[3];
    }
    const float rsum = rs_lds[(wr * 16 + l15) * 2 + 0] + rs_lds[(wr * 16 + l15) * 2 + 1];
    const float inv = 1.0f / (fmaxf(fabsf(rsum), fl_reg) + 1e-6f);
    union { float f; int i; } uc; uc.f = inv;
    float invr[4];
    #pragma unroll
    for (int r = 0; r < 4; ++r) {
      union { float f; int i; } ur;
      ur.i = __builtin_amdgcn_ds_bpermute((lg * 4 + r) * 4, uc.i);
      invr[r] = ur.f;
    }
    #pragma unroll
    for (int r = 0; r < 4; ++r) {
      const size_t orow = (size_t)(b * SLEN + i0 + wr * 16 + lg * 4 + r) * DMODEL + h * DHEAD;
      #pragma unroll
      for (int cf = 0; cf < 8; ++cf)
        out[orow + cf * 16 + l15] = hacc[cf][r] * invr[r];
    }
  }
}

// ---------------- Kernel 4: in-place LayerNorm on d_out ---------------------
__global__ __launch_bounds__(256)
void ln_kernel(float* __restrict__ out, const float* __restrict__ gamma) {
  const int row = blockIdx.x;
  const int tid = threadIdx.x;
  float* x = out + (size_t)row * DMODEL;
  f32x4 xv = ((const f32x4*)x)[tid];
  float s = xv[0] + xv[1] + xv[2] + xv[3];
  float qq = xv[0] * xv[0] + xv[1] * xv[1] + xv[2] * xv[2] + xv[3] * xv[3];
  #pragma unroll
  for (int m = 1; m < 64; m <<= 1) { s += __shfl_xor(s, m); qq += __shfl_xor(qq, m); }
  __shared__ float ss[4], sq[4];
  const int wid = tid >> 6;
  if ((tid & 63) == 0) { ss[wid] = s; sq[wid] = qq; }
  __syncthreads();
  s = ss[0] + ss[1] + ss[2] + ss[3];
  qq = sq[0] + sq[1] + sq[2] + sq[3];
  const float mu = s * (1.f / 1024.f);
  const float var = qq * (1.f / 1024.f) - mu * mu;
  const float rstd = rsqrtf(var + 1e-5f);
  f32x4 g = ((const f32x4*)gamma)[tid];
  f32x4 ov;
  ov[0] = (xv[0] - mu) * rstd * g[0];
  ov[1] = (xv[1] - mu) * rstd * g[1];
  ov[2] = (xv[2] - mu) * rstd * g[2];
  ov[3] = (xv[3] - mu) * rstd * g[3];
  ((f32x4*)x)[tid] = ov;
}

extern "C" void kernel_launch(void* const* d_in, const int* in_sizes, int n_in,
                              void* d_out, int out_size, void* d_ws, size_t ws_size,
                              hipStream_t stream) {
  (void)in_sizes; (void)n_in; (void)out_size;
  const float* q   = (const float*)d_in[0];
  const float* k   = (const float*)d_in[1];
  const float* v   = (const float*)d_in[2];
  const float* igw = (const float*)d_in[3];
  const float* igb = (const float*)d_in[4];
  const float* fgw = (const float*)d_in[5];
  const float* fgb = (const float*)d_in[6];
  const float* lns = (const float*)d_in[7];
  float* out = (float*)d_out;

  float* gpre  = (float*)d_ws;           // 65536 f32
  float* a_g   = gpre + 65536;           // 32768
  float* ms_g  = a_g + 32768;            // 32768
  float* fl_g  = ms_g + 32768;           // 32768
  float* mt64  = fl_g + 32768;           // 512   (16 x 32)
  float* mt128 = mt64 + 512;             // 256   (16 x 16)
  float* Mg_g  = mt128 + 256;            // 256
  float* pkt   = Mg_g + 256;             // 32768 (256 x 128)
  float* pkx   = pkt + 32768;            // 32768
  unsigned short* GXs = (unsigned short*)(pkx + 32768);  // 256 x 16384 fp16 = 8MB
  // total = 921,600 B + 8,388,608 B ≈ 9.31 MB

  const bool big = ws_size >= (size_t)10 * 1024 * 1024;

  gates_kernel<<<dim3(1024), dim3(256), 0, stream>>>(q, k, v, igw, fgw, gpre);
  scan_kernel<<<dim3(16), dim3(256), 0, stream>>>(gpre, igb, fgb, a_g, ms_g, fl_g,
                                                  mt64, mt128, Mg_g);
  if (big) {
    p1_kernel<<<dim3(16, 16), dim3(512), 0, stream>>>(k, v, a_g, mt128, GXs, pkt);
    p2_kernel<<<dim3(9, 16), dim3(256), 0, stream>>>(mt128, GXs, pkt, pkx);
    p3_kernel<<<dim3(512), dim3(512), 0, stream>>>(q, k, v, a_g, ms_g, fl_g,
                                                   Mg_g, pkx, GXs, out);
  } else {
    mlstm_main<<<dim3(512), dim3(512), 0, stream>>>(q, k, v, a_g, ms_g, fl_g, mt64, out);
  }
  ln_kernel<<<dim3(4096), dim3(256), 0, stream>>>(out, lns);
}